// Round 15
// baseline (305.819 us; speedup 1.0000x reference)
//
#include <hip/hip_runtime.h>
#include <math.h>

typedef unsigned short u16;
typedef unsigned int   u32;

typedef __bf16 bf16x8 __attribute__((ext_vector_type(8)));
typedef float  f32x4  __attribute__((ext_vector_type(4)));

#define C_DIM 256
#define D_DIM 8192
#define HIDD  4096
#define Y1D   2048

__device__ __forceinline__ u16 f2bf(float f) {
    union { float f; u32 u; } v; v.f = f;
    u32 r = v.u + 0x7fffu + ((v.u >> 16) & 1u);   // RNE
    return (u16)(r >> 16);
}
__device__ __forceinline__ float geluf(float x) {
    return 0.5f * x * (1.0f + erff(x * 0.70710678118654752f));
}
// LDS swizzle: 16B chunk kg within a 64B row, XOR'd by row bits -> low-conflict reads
__device__ __forceinline__ int swz(int row, int kg) {
    return row * 64 + (((kg) ^ ((row >> 1) & 3)) << 4);
}
// fp32 LDS swizzle for the filter row buffer
__device__ __forceinline__ int xsw(int t) {
    int ch = t >> 2;
    return (((ch ^ ((ch >> 3) & 7))) << 2) | (t & 3);
}
// async global->LDS, 16B per lane; lds dest wave-uniform base (lane*16 implicit)
__device__ __forceinline__ void gload16(const void* g, void* l) {
    __builtin_amdgcn_global_load_lds(
        (const __attribute__((address_space(1))) void*)g,
        (__attribute__((address_space(3))) void*)l, 16, 0, 0);
}

// ---- per-row: weight-net coefs (fused), Z=FIR(c,X-mu) bf16, Xo bf16, X bf16 ----
__global__ __launch_bounds__(256) void filterk(const float* __restrict__ X,
                                               const float* __restrict__ w1,
                                               const float* __restrict__ b1,
                                               const float* __restrict__ w2,
                                               const float* __restrict__ b2,
                                               u16* __restrict__ Zb,
                                               u16* __restrict__ Xob,
                                               u16* __restrict__ Xb) {
    __shared__ float Xl[8240];
    __shared__ float wl[65];
    __shared__ float cl[40];
    __shared__ float red[4];
    int i = blockIdx.x, tid = threadIdx.x;
    int lane = tid & 63, wv = tid >> 6;
    const float* row = X + (size_t)i * D_DIM;
    float s = 0.f;
    #pragma unroll
    for (int q = 0; q < 8; ++q) {
        int t = tid * 32 + q * 4;
        float4 v = *(const float4*)(row + t);
        s += v.x + v.y + v.z + v.w;
        *(float4*)(Xl + xsw(t)) = v;
    }
    float w1l = w1[lane], b1l = b1[lane], w2l = w2[lane], b2l = b2[0];
    for (int li = wv; li < 65; li += 4) {
        float lag = (float)(li - 32);
        float h = geluf(lag * w1l + b1l);
        float p = h * w2l;
        #pragma unroll
        for (int off = 32; off; off >>= 1) p += __shfl_xor(p, off);
        if (lane == 0) wl[li] = p + b2l;
    }
    #pragma unroll
    for (int off = 32; off; off >>= 1) s += __shfl_xor(s, off);
    if (lane == 0) red[wv] = s;
    __syncthreads();
    if (tid <= 32) {
        cl[tid] = (tid == 0) ? wl[32] / (float)D_DIM
                             : (wl[32 - tid] + wl[32 + tid]) / ((float)D_DIM - (float)tid);
    }
    if (tid == 33) {
        float ssum = wl[32] / (float)D_DIM;
        for (int k = 1; k <= 32; ++k) ssum += (wl[32 - k] + wl[32 + k]) / ((float)D_DIM - (float)k);
        cl[33] = ssum;
    }
    float mu = (red[0] + red[1] + red[2] + red[3]) * (1.f / (float)D_DIM);
    if (tid < 10) {
        float4 mv = make_float4(mu, mu, mu, mu);
        *(float4*)(Xl + xsw(D_DIM + tid * 4)) = mv;
    }
    __syncthreads();
    float csum = cl[33];
    #pragma unroll
    for (int ch = 0; ch < 8; ++ch) {
        int t4 = tid * 32 + ch * 4;
        float w[40] __attribute__((aligned(16)));
        #pragma unroll
        for (int g = 0; g < 10; ++g)
            *(float4*)(w + g * 4) = *(const float4*)(Xl + xsw(t4 + g * 4));
        u16 zb[4], xo[4], xb[4];
        #pragma unroll
        for (int j = 0; j < 4; ++j) {
            float a = 0.f;
            #pragma unroll
            for (int k = 0; k < 33; ++k) a = fmaf(cl[k], w[j + k], a);
            zb[j] = f2bf(a - mu * csum);
            xo[j] = f2bf(w[j] - mu);
            xb[j] = f2bf(w[j]);
        }
        uint2 zp, op, bp;
        zp.x = (u32)zb[0] | ((u32)zb[1] << 16); zp.y = (u32)zb[2] | ((u32)zb[3] << 16);
        op.x = (u32)xo[0] | ((u32)xo[1] << 16); op.y = (u32)xo[2] | ((u32)xo[3] << 16);
        bp.x = (u32)xb[0] | ((u32)xb[1] << 16); bp.y = (u32)xb[2] | ((u32)xb[3] << 16);
        *(uint2*)(Zb  + (size_t)i * D_DIM + t4) = zp;
        *(uint2*)(Xob + (size_t)i * D_DIM + t4) = op;
        *(uint2*)(Xb  + (size_t)i * D_DIM + t4) = bp;
    }
}

// ---- barrier-free register GEMM (fc1/fc2): 8 waves x (64m x 32n), no LDS ------
// 512 thr. Per wave per kstep: 4 A dwordx4 (L2-hot, ks-clustered) + 16 B dword
// (64B-coalesced per kg row; wm-redundant reads L2-absorbed) + 8 cvt_pk + 8 MFMA.
// ZERO sync instructions: compiler emits counted per-use waitcnts; ~16 waves/CU
// of independent streams (fill-kernel regime). Fixes R13: per-wave state is
// acc32+frags (~90 VGPR), not M=256-per-wave.
template<int KS>
__global__ __launch_bounds__(512) void gemm_r(
    const u16* __restrict__ A, int lda,
    const float* __restrict__ B, int ldb,
    int N, int sliceLen, int nHalf, long long bHalfOff,
    u16* __restrict__ outB, int partStride)
{
    const int tid = threadIdx.x;
    const int bid = blockIdx.x;
    const int ks  = bid % KS;              // ks fastest -> same-ks blocks share an XCD
    const int nb0 = (bid / KS) * 64;
    const int k0base = ks * sliceLen;
    const int ksteps = sliceLen >> 5;
    const int lane = tid & 63, wid = tid >> 6;
    const int wm = wid >> 1, wn = wid & 1;
    const int l15 = lane & 15, kg = lane >> 4;

    const int nw   = nb0 + wn * 32;        // wave's 32-col base (wave-uniform)
    const int inH2 = (nw >= nHalf) ? 1 : 0;
    const int nwB  = nw - (inH2 ? nHalf : 0);

    // A fragment base: row = wm*64 + mi*16 + l15, k = k0base + kg*8 (16B contig)
    const u16* Ap = A + (size_t)(wm * 64 + l15) * lda + k0base + kg * 8;
    // B base: row k0base + kg*8 + j, col nwB + ni*16 + l15
    const float* Bp = B + (inH2 ? (size_t)bHalfOff : 0)
                    + (size_t)(k0base + kg * 8) * ldb + nwB + l15;

    f32x4 acc[4][2];
    #pragma unroll
    for (int mi = 0; mi < 4; ++mi)
        #pragma unroll
        for (int ni = 0; ni < 2; ++ni) { f32x4 zz = {0.f, 0.f, 0.f, 0.f}; acc[mi][ni] = zz; }

    #pragma unroll 2
    for (int kt = 0; kt < ksteps; ++kt) {
        const u16* ap = Ap + (kt << 5);
        bf16x8 af[4];
        #pragma unroll
        for (int mi = 0; mi < 4; ++mi)
            af[mi] = *(const bf16x8*)(ap + (size_t)mi * 16 * lda);
        const float* bp = Bp + (size_t)(kt << 5) * ldb;
        bf16x8 bfr[2];
        #pragma unroll
        for (int ni = 0; ni < 2; ++ni) {
            float b[8];
            #pragma unroll
            for (int j = 0; j < 8; ++j) b[j] = bp[(size_t)j * ldb + ni * 16];
            union { u32 u[4]; bf16x8 v; } pk;
            #pragma unroll
            for (int j = 0; j < 4; ++j)
                asm("v_cvt_pk_bf16_f32 %0, %1, %2"
                    : "=v"(pk.u[j]) : "v"(b[2 * j]), "v"(b[2 * j + 1]));
            bfr[ni] = pk.v;
        }
        #pragma unroll
        for (int mi = 0; mi < 4; ++mi)
            #pragma unroll
            for (int ni = 0; ni < 2; ++ni)
                acc[mi][ni] = __builtin_amdgcn_mfma_f32_16x16x32_bf16(af[mi], bfr[ni], acc[mi][ni], 0, 0, 0);
    }

    // epilogue: C/D layout col=lane&15, row=(lane>>4)*4+reg
    const int rq = lane >> 4;
    #pragma unroll
    for (int mi = 0; mi < 4; ++mi)
        #pragma unroll
        for (int ni = 0; ni < 2; ++ni)
            #pragma unroll
            for (int r = 0; r < 4; ++r) {
                int m = wm * 64 + mi * 16 + rq * 4 + r;
                int n = nw + ni * 16 + l15;
                outB[(size_t)ks * partStride + (size_t)m * N + n] = f2bf(acc[mi][ni][r]);
            }
}

// ------- unified bf16 MFMA GEMM (cov / h / proj; R9-proven path) ---------------
template<int MODE, int ASRC, int BSRC, int BN, int KS>
__global__ __launch_bounds__(512) void gemm_u(
    const void* __restrict__ Av, int lda,
    const void* __restrict__ Bv, int ldb,
    int N, int sliceLen, int nHalf, long long bHalfOff,
    const float* __restrict__ Vadd, const float* __restrict__ bias,
    float* __restrict__ outF, u16* __restrict__ outB,
    int ldc, int partStride)
{
    constexpr int NI = BN / 32;
    __shared__ u16 Alds[2][256 * 32];
    __shared__ u16 Blds[2][BN * 32];
    const int tid = threadIdx.x;
    const int bid = blockIdx.x;
    const int ks  = bid % KS;
    const int nb0 = (bid / KS) * BN;
    const int mt  = blockIdx.y;
    const int k0base = ks * sliceLen;
    const int ksteps = sliceLen >> 5;
    const int lane = tid & 63, wid = tid >> 6;
    const int wm = wid >> 1, wn = wid & 1;
    const int l15 = lane & 15, kg = lane >> 4;

    const int inH2 = (nb0 >= nHalf) ? 1 : 0;
    const int nbB  = nb0 - (inH2 ? nHalf : 0);

    const u16* gA0 = nullptr; const u16* gA1 = nullptr;
    {
        int r0 = wid * 32 + (lane >> 2);
        int r1 = r0 + 16;
        int c0 = (lane & 3) ^ ((r0 >> 1) & 3);
        int c1 = (lane & 3) ^ ((r1 >> 1) & 3);
        gA0 = (const u16*)Av + (size_t)(mt * 256 + r0) * lda + k0base + c0 * 8;
        gA1 = (const u16*)Av + (size_t)(mt * 256 + r1) * lda + k0base + c1 * 8;
    }
    const int sArow = tid >> 1, sAe = (tid & 1) * 16;
    const float* ApF = (const float*)Av + (size_t)(mt * 256 + sArow) * lda + sAe + k0base;
    const int aw0 = swz(sArow, sAe >> 3);
    const int aw1 = swz(sArow, (sAe >> 3) + 1);
    float4 fa0, fa1, fa2, fa3;

    const int n2 = (tid & 31) * 2;
    const int k4 = ((tid >> 5) & 7) * 4;
    const float* BpF = (const float*)Bv + (inH2 ? (size_t)bHalfOff : 0)
                     + (size_t)(k0base + k4) * ldb + nbB + n2;
    const int bwc0 = swz(n2,     k4 >> 3) + (k4 & 4) * 2;
    const int bwc1 = swz(n2 + 1, k4 >> 3) + (k4 & 4) * 2;
    float2 Lb0, Lb1, Lb2, Lb3;
    const u16* gB0 = nullptr;
    if constexpr (BSRC == 1) {
        int tr = wid * 16 + (lane >> 2);
        int c  = (lane & 3) ^ ((tr >> 1) & 3);
        gB0 = (const u16*)Bv + (size_t)(nb0 + tr) * ldb + k0base + c * 8;
    }
    const int sBk = tid >> 4, sBn2 = (tid & 15) * 2;
    const u16* BpH = (const u16*)Bv + (size_t)(k0base + sBk) * ldb + nbB + sBn2;
    const int bh0 = swz(sBn2,     sBk >> 3) + (sBk & 7) * 2;
    const int bh1 = swz(sBn2 + 1, sBk >> 3) + (sBk & 7) * 2;
    u32 bhv = 0;

    int aoff[4], boff[NI];
    #pragma unroll
    for (int mi = 0; mi < 4; ++mi) { int r = wm * 64 + mi * 16 + l15; aoff[mi] = swz(r, kg); }
    #pragma unroll
    for (int ni = 0; ni < NI; ++ni) { int r = wn * (BN / 2) + ni * 16 + l15; boff[ni] = swz(r, kg); }

    auto stageGL = [&](int kt, int pb) {
        if constexpr (ASRC == 0) {
            char* ab = (char*)&Alds[pb][0] + wid * 2048;
            gload16(gA0 + (kt << 5), ab);
            gload16(gA1 + (kt << 5), ab + 1024);
        }
        if constexpr (BSRC == 1) {
            if (wid < BN / 16) {
                char* bb = (char*)&Blds[pb][0] + wid * 1024;
                gload16(gB0 + (kt << 5), bb);
            }
        }
    };
    auto loadA = [&](int kt) {
        const float* ap = ApF + (kt << 5);
        fa0 = *(const float4*)(ap);     fa1 = *(const float4*)(ap + 4);
        fa2 = *(const float4*)(ap + 8); fa3 = *(const float4*)(ap + 12);
    };
    auto writeA = [&](int pb) {
        char* AB = (char*)&Alds[pb][0];
        int4 w0, w1;
        w0.x = (int)((u32)f2bf(fa0.x) | ((u32)f2bf(fa0.y) << 16));
        w0.y = (int)((u32)f2bf(fa0.z) | ((u32)f2bf(fa0.w) << 16));
        w0.z = (int)((u32)f2bf(fa1.x) | ((u32)f2bf(fa1.y) << 16));
        w0.w = (int)((u32)f2bf(fa1.z) | ((u32)f2bf(fa1.w) << 16));
        w1.x = (int)((u32)f2bf(fa2.x) | ((u32)f2bf(fa2.y) << 16));
        w1.y = (int)((u32)f2bf(fa2.z) | ((u32)f2bf(fa2.w) << 16));
        w1.z = (int)((u32)f2bf(fa3.x) | ((u32)f2bf(fa3.y) << 16));
        w1.w = (int)((u32)f2bf(fa3.z) | ((u32)f2bf(fa3.w) << 16));
        *(int4*)(AB + aw0) = w0;
        *(int4*)(AB + aw1) = w1;
    };
    auto loadB = [&](int kt) {
        if constexpr (BSRC == 0) {
            if (tid < 256) {
                const float* bp = BpF + (size_t)(kt << 5) * ldb;
                Lb0 = *(const float2*)(bp);
                Lb1 = *(const float2*)(bp + ldb);
                Lb2 = *(const float2*)(bp + 2 * ldb);
                Lb3 = *(const float2*)(bp + 3 * ldb);
            }
        } else if constexpr (BSRC == 2) {
            bhv = *(const u32*)(BpH + (size_t)(kt << 5) * ldb);
        }
    };
    auto writeB = [&](int pb) {
        char* BB = (char*)&Blds[pb][0];
        if constexpr (BSRC == 0) {
            if (tid < 256) {
                uint2 p0, p1;
                p0.x = (u32)f2bf(Lb0.x) | ((u32)f2bf(Lb1.x) << 16);
                p0.y = (u32)f2bf(Lb2.x) | ((u32)f2bf(Lb3.x) << 16);
                p1.x = (u32)f2bf(Lb0.y) | ((u32)f2bf(Lb1.y) << 16);
                p1.y = (u32)f2bf(Lb2.y) | ((u32)f2bf(Lb3.y) << 16);
                *(uint2*)(BB + bwc0) = p0;
                *(uint2*)(BB + bwc1) = p1;
            }
        } else if constexpr (BSRC == 2) {
            *(u16*)(BB + bh0) = (u16)(bhv & 0xffffu);
            *(u16*)(BB + bh1) = (u16)(bhv >> 16);
        }
    };

    f32x4 acc[4][NI];
    #pragma unroll
    for (int mi = 0; mi < 4; ++mi)
        #pragma unroll
        for (int ni = 0; ni < NI; ++ni) { f32x4 zz = {0.f, 0.f, 0.f, 0.f}; acc[mi][ni] = zz; }

    auto mfmaStep = [&](int pb) {
        const char* AB = (const char*)&Alds[pb][0];
        const char* BB = (const char*)&Blds[pb][0];
        bf16x8 af[4], bfr[NI];
        #pragma unroll
        for (int mi = 0; mi < 4; ++mi) af[mi] = *(const bf16x8*)(AB + aoff[mi]);
        #pragma unroll
        for (int ni = 0; ni < NI; ++ni) bfr[ni] = *(const bf16x8*)(BB + boff[ni]);
        #pragma unroll
        for (int mi = 0; mi < 4; ++mi)
            #pragma unroll
            for (int ni = 0; ni < NI; ++ni)
                acc[mi][ni] = __builtin_amdgcn_mfma_f32_16x16x32_bf16(af[mi], bfr[ni], acc[mi][ni], 0, 0, 0);
    };

    stageGL(0, 0);
    if constexpr (ASRC == 1) { loadA(0); writeA(0); loadA(1); }
    if constexpr (BSRC == 0 || BSRC == 2) { loadB(0); writeB(0); loadB(1); }
    __syncthreads();
    for (int kt = 0; kt < ksteps; ++kt) {
        const int pb = kt & 1;
        if (kt + 1 < ksteps) {
            stageGL(kt + 1, pb ^ 1);
            if constexpr (ASRC == 1) writeA(pb ^ 1);
            if constexpr (BSRC == 0 || BSRC == 2) writeB(pb ^ 1);
        }
        if (kt + 2 < ksteps) {
            if constexpr (ASRC == 1) loadA(kt + 2);
            if constexpr (BSRC == 0 || BSRC == 2) loadB(kt + 2);
        }
        mfmaStep(pb);
        __syncthreads();
    }

    const int rq = lane >> 4;
    #pragma unroll
    for (int mi = 0; mi < 4; ++mi)
        #pragma unroll
        for (int ni = 0; ni < NI; ++ni)
            #pragma unroll
            for (int r = 0; r < 4; ++r) {
                int m = wm * 64 + mi * 16 + rq * 4 + r;
                int n = nb0 + wn * (BN / 2) + ni * 16 + l15;
                float v = acc[mi][ni][r];
                if (MODE == 0)
                    outB[(size_t)ks * partStride + (size_t)m * N + n] = f2bf(v);
                else if (MODE == 2)
                    outF[(size_t)(mt * 256 + m) * ldc + n] = v;
                else {
                    float h = geluf(v + Vadd[(size_t)m * N + n] + bias[n]);
                    outB[(size_t)m * ldc + n] = f2bf(h);
                }
            }
}

// -------- sum 32 bf16 cov partials -> covbf ------------------------------------
__global__ __launch_bounds__(256) void reduce_cov(const u16* __restrict__ parts,
                                                  u16* __restrict__ out) {
    int i8 = (blockIdx.x * 256 + threadIdx.x) * 8;
    float s[8] = {};
    #pragma unroll
    for (int sl = 0; sl < 32; ++sl) {
        uint4 v = *(const uint4*)(parts + (size_t)sl * 65536 + i8);
        u32 w[4] = {v.x, v.y, v.z, v.w};
        #pragma unroll
        for (int j = 0; j < 4; ++j) {
            union { u32 u; float f; } lo, hi;
            lo.u = (w[j] & 0xffffu) << 16; hi.u = w[j] & 0xffff0000u;
            s[2 * j] += lo.f; s[2 * j + 1] += hi.f;
        }
    }
    uint4 pk;
    pk.x = (u32)f2bf(s[0]) | ((u32)f2bf(s[1]) << 16);
    pk.y = (u32)f2bf(s[2]) | ((u32)f2bf(s[3]) << 16);
    pk.z = (u32)f2bf(s[4]) | ((u32)f2bf(s[5]) << 16);
    pk.w = (u32)f2bf(s[6]) | ((u32)f2bf(s[7]) << 16);
    *(uint4*)(out + i8) = pk;
}

// -------- fc1 partials (8 slices of 256x8192) -> V fp32 (n<4096) / Ubf (n>=4096)
__global__ __launch_bounds__(256) void reduce_vu(const u16* __restrict__ parts,
                                                 float* __restrict__ V,
                                                 u16* __restrict__ U) {
    int i8 = (blockIdx.x * 256 + threadIdx.x) * 8;
    int m = i8 >> 13, n = i8 & 8191;
    float s[8] = {};
    #pragma unroll
    for (int sl = 0; sl < 8; ++sl) {
        uint4 v = *(const uint4*)(parts + (size_t)sl * (256 * 8192) + i8);
        u32 w[4] = {v.x, v.y, v.z, v.w};
        #pragma unroll
        for (int j = 0; j < 4; ++j) {
            union { u32 u; float f; } lo, hi;
            lo.u = (w[j] & 0xffffu) << 16; hi.u = w[j] & 0xffff0000u;
            s[2 * j] += lo.f; s[2 * j + 1] += hi.f;
        }
    }
    if (n < 4096) {
        float* vp = V + (size_t)m * 4096 + n;
        *(float4*)(vp)     = make_float4(s[0], s[1], s[2], s[3]);
        *(float4*)(vp + 4) = make_float4(s[4], s[5], s[6], s[7]);
    } else {
        uint4 pk;
        pk.x = (u32)f2bf(s[0]) | ((u32)f2bf(s[1]) << 16);
        pk.y = (u32)f2bf(s[2]) | ((u32)f2bf(s[3]) << 16);
        pk.z = (u32)f2bf(s[4]) | ((u32)f2bf(s[5]) << 16);
        pk.w = (u32)f2bf(s[6]) | ((u32)f2bf(s[7]) << 16);
        *(uint4*)(U + (size_t)m * 4096 + (n - 4096)) = pk;
    }
}

// -------- fc2 partials (16 slices) + bias + gelu -> of32 fp32 ------------------
__global__ __launch_bounds__(256) void reduce_fc16(const u16* __restrict__ parts,
                                                   const float* __restrict__ bias,
                                                   float* __restrict__ outF) {
    int i8 = (blockIdx.x * 256 + threadIdx.x) * 8;
    int col = i8 & (Y1D - 1);
    float s[8] = {};
    #pragma unroll
    for (int sl = 0; sl < 16; ++sl) {
        uint4 v = *(const uint4*)(parts + (size_t)sl * (256 * Y1D) + i8);
        u32 w[4] = {v.x, v.y, v.z, v.w};
        #pragma unroll
        for (int j = 0; j < 4; ++j) {
            union { u32 u; float f; } lo, hi;
            lo.u = (w[j] & 0xffffu) << 16; hi.u = w[j] & 0xffff0000u;
            s[2 * j] += lo.f; s[2 * j + 1] += hi.f;
        }
    }
    float4 b0 = *(const float4*)(bias + col);
    float4 b1 = *(const float4*)(bias + col + 4);
    s[0] = geluf(s[0] + b0.x); s[1] = geluf(s[1] + b0.y);
    s[2] = geluf(s[2] + b0.z); s[3] = geluf(s[3] + b0.w);
    s[4] = geluf(s[4] + b1.x); s[5] = geluf(s[5] + b1.y);
    s[6] = geluf(s[6] + b1.z); s[7] = geluf(s[7] + b1.w);
    *(float4*)(outF + i8)     = make_float4(s[0], s[1], s[2], s[3]);
    *(float4*)(outF + i8 + 4) = make_float4(s[4], s[5], s[6], s[7]);
}

extern "C" void kernel_launch(void* const* d_in, const int* in_sizes, int n_in,
                              void* d_out, int out_size, void* d_ws, size_t ws_size,
                              hipStream_t stream) {
    const float* X     = (const float*)d_in[0];
    const float* wn_w1 = (const float*)d_in[1];
    const float* wn_b1 = (const float*)d_in[2];
    const float* wn_w2 = (const float*)d_in[3];
    const float* wn_b2 = (const float*)d_in[4];
    const float* fc1_w = (const float*)d_in[5];
    const float* fc1_b = (const float*)d_in[6];
    const float* fc2_w = (const float*)d_in[7];
    const float* fc2_b = (const float*)d_in[8];
    const float* proj  = (const float*)d_in[9];

    char* ws = (char*)d_ws;
    size_t off = 0;
    auto alloc = [&](size_t bytes) { size_t o = off; off += (bytes + 255) & ~(size_t)255; return o; };
    u16*   Zb    = (u16*)  (ws + alloc((size_t)C_DIM * D_DIM * 2));
    u16*   Xob   = (u16*)  (ws + alloc((size_t)C_DIM * D_DIM * 2));
    u16*   Xb    = (u16*)  (ws + alloc((size_t)C_DIM * D_DIM * 2));
    u16*   covp  = (u16*)  (ws + alloc((size_t)32 * 65536 * 2));
    u16*   covbf = (u16*)  (ws + alloc((size_t)65536 * 2));
    u16*   p1b   = (u16*)  (ws + alloc((size_t)8 * C_DIM * D_DIM * 2));
    float* Vf    = (float*)(ws + alloc((size_t)C_DIM * HIDD * 4));
    u16*   Ubf   = (u16*)  (ws + alloc((size_t)C_DIM * HIDD * 2));
    u16*   hbf   = (u16*)  (ws + alloc((size_t)C_DIM * HIDD * 2));
    u16*   p2b   = (u16*)  (ws + alloc((size_t)16 * C_DIM * Y1D * 2));
    float* of32  = (float*)(ws + alloc((size_t)C_DIM * Y1D * 4));

    filterk<<<C_DIM, 256, 0, stream>>>(X, wn_w1, wn_b1, wn_w2, wn_b2, Zb, Xob, Xb);
    // cov partials: Zb @ Xob^T (A+B gload_lds), KS=32 -> 128 blocks
    gemm_u<0, 0, 1, 64, 32><<<128, 512, 0, stream>>>(Zb, D_DIM, Xob, D_DIM,
        C_DIM, D_DIM / 32, C_DIM, 0, nullptr, nullptr, nullptr, covp, 0, 65536);
    reduce_cov<<<32, 256, 0, stream>>>(covp, covbf);
    // fc1 fused: Xb @ [W_top | W_bot] -> 8 bf16 K-slice partials (register GEMM)
    gemm_r<8><<<(2 * HIDD / 64) * 8, 512, 0, stream>>>(Xb, D_DIM, fc1_w, HIDD,
        2 * HIDD, D_DIM / 8, HIDD, (long long)D_DIM * HIDD, p1b, C_DIM * 2 * HIDD);
    reduce_vu<<<1024, 256, 0, stream>>>(p1b, Vf, Ubf);
    // h = gelu(V + cov @ U + b1)  (K=256, A gload, B bf16 NN)
    gemm_u<3, 0, 2, 32, 1><<<HIDD / 32, 512, 0, stream>>>(covbf, C_DIM, Ubf, HIDD,
        HIDD, C_DIM, HIDD, 0, Vf, fc1_b, nullptr, hbf, HIDD, 0);
    // fc2: h @ fc2_w, KS=16 -> 512 blocks (register GEMM)
    gemm_r<16><<<(Y1D / 64) * 16, 512, 0, stream>>>(hbf, HIDD, fc2_w, Y1D,
        Y1D, HIDD / 16, 1 << 30, 0, p2b, C_DIM * Y1D);
    reduce_fc16<<<C_DIM * Y1D / 8 / 256, 256, 0, stream>>>(p2b, fc2_b, of32);
    // out = proj @ o   (A fp32 reg-convert; M=512 -> 2 m-tiles)
    gemm_u<2, 1, 0, 64, 1><<<dim3(Y1D / 64, 2), 512, 0, stream>>>(proj, C_DIM, of32, Y1D,
        Y1D, C_DIM, Y1D, 0, nullptr, nullptr, (float*)d_out, nullptr, Y1D, 0);
}

// Round 16
// 225.525 us; speedup vs baseline: 1.3560x; 1.3560x over previous
//
#include <hip/hip_runtime.h>
#include <math.h>

typedef unsigned short u16;
typedef unsigned int   u32;

typedef __bf16 bf16x8 __attribute__((ext_vector_type(8)));
typedef float  f32x4  __attribute__((ext_vector_type(4)));

#define C_DIM 256
#define D_DIM 8192
#define HIDD  4096
#define Y1D   2048

__device__ __forceinline__ u16 f2bf(float f) {
    union { float f; u32 u; } v; v.f = f;
    u32 r = v.u + 0x7fffu + ((v.u >> 16) & 1u);   // RNE
    return (u16)(r >> 16);
}
__device__ __forceinline__ float geluf(float x) {
    return 0.5f * x * (1.0f + erff(x * 0.70710678118654752f));
}
// LDS swizzle: 16B chunk kg within a 64B row, XOR'd by row bits -> low-conflict reads
__device__ __forceinline__ int swz(int row, int kg) {
    return row * 64 + (((kg) ^ ((row >> 1) & 3)) << 4);
}
// fp32 LDS swizzle for the filter row buffer
__device__ __forceinline__ int xsw(int t) {
    int ch = t >> 2;
    return (((ch ^ ((ch >> 3) & 7))) << 2) | (t & 3);
}
// async global->LDS, 16B per lane; lds dest wave-uniform base (lane*16 implicit)
__device__ __forceinline__ void gload16(const void* g, void* l) {
    __builtin_amdgcn_global_load_lds(
        (const __attribute__((address_space(1))) void*)g,
        (__attribute__((address_space(3))) void*)l, 16, 0, 0);
}

// ---- per-row: weight-net coefs (fused), Z=FIR(c,X-mu) bf16, Xo bf16, X bf16 ----
__global__ __launch_bounds__(256) void filterk(const float* __restrict__ X,
                                               const float* __restrict__ w1,
                                               const float* __restrict__ b1,
                                               const float* __restrict__ w2,
                                               const float* __restrict__ b2,
                                               u16* __restrict__ Zb,
                                               u16* __restrict__ Xob,
                                               u16* __restrict__ Xb) {
    __shared__ float Xl[8240];
    __shared__ float wl[65];
    __shared__ float cl[40];
    __shared__ float red[4];
    int i = blockIdx.x, tid = threadIdx.x;
    int lane = tid & 63, wv = tid >> 6;
    const float* row = X + (size_t)i * D_DIM;
    float s = 0.f;
    #pragma unroll
    for (int q = 0; q < 8; ++q) {
        int t = tid * 32 + q * 4;
        float4 v = *(const float4*)(row + t);
        s += v.x + v.y + v.z + v.w;
        *(float4*)(Xl + xsw(t)) = v;
    }
    float w1l = w1[lane], b1l = b1[lane], w2l = w2[lane], b2l = b2[0];
    for (int li = wv; li < 65; li += 4) {
        float lag = (float)(li - 32);
        float h = geluf(lag * w1l + b1l);
        float p = h * w2l;
        #pragma unroll
        for (int off = 32; off; off >>= 1) p += __shfl_xor(p, off);
        if (lane == 0) wl[li] = p + b2l;
    }
    #pragma unroll
    for (int off = 32; off; off >>= 1) s += __shfl_xor(s, off);
    if (lane == 0) red[wv] = s;
    __syncthreads();
    if (tid <= 32) {
        cl[tid] = (tid == 0) ? wl[32] / (float)D_DIM
                             : (wl[32 - tid] + wl[32 + tid]) / ((float)D_DIM - (float)tid);
    }
    if (tid == 33) {
        float ssum = wl[32] / (float)D_DIM;
        for (int k = 1; k <= 32; ++k) ssum += (wl[32 - k] + wl[32 + k]) / ((float)D_DIM - (float)k);
        cl[33] = ssum;
    }
    float mu = (red[0] + red[1] + red[2] + red[3]) * (1.f / (float)D_DIM);
    if (tid < 10) {
        float4 mv = make_float4(mu, mu, mu, mu);
        *(float4*)(Xl + xsw(D_DIM + tid * 4)) = mv;
    }
    __syncthreads();
    float csum = cl[33];
    #pragma unroll
    for (int ch = 0; ch < 8; ++ch) {
        int t4 = tid * 32 + ch * 4;
        float w[40] __attribute__((aligned(16)));
        #pragma unroll
        for (int g = 0; g < 10; ++g)
            *(float4*)(w + g * 4) = *(const float4*)(Xl + xsw(t4 + g * 4));
        u16 zb[4], xo[4], xb[4];
        #pragma unroll
        for (int j = 0; j < 4; ++j) {
            float a = 0.f;
            #pragma unroll
            for (int k = 0; k < 33; ++k) a = fmaf(cl[k], w[j + k], a);
            zb[j] = f2bf(a - mu * csum);
            xo[j] = f2bf(w[j] - mu);
            xb[j] = f2bf(w[j]);
        }
        uint2 zp, op, bp;
        zp.x = (u32)zb[0] | ((u32)zb[1] << 16); zp.y = (u32)zb[2] | ((u32)zb[3] << 16);
        op.x = (u32)xo[0] | ((u32)xo[1] << 16); op.y = (u32)xo[2] | ((u32)xo[3] << 16);
        bp.x = (u32)xb[0] | ((u32)xb[1] << 16); bp.y = (u32)xb[2] | ((u32)xb[3] << 16);
        *(uint2*)(Zb  + (size_t)i * D_DIM + t4) = zp;
        *(uint2*)(Xob + (size_t)i * D_DIM + t4) = op;
        *(uint2*)(Xb  + (size_t)i * D_DIM + t4) = bp;
    }
}

// ------- unified bf16 MFMA GEMM (R8/R12-proven structure, higher split-K) ------
// MODE 0: bf16 split-K partials; MODE 2: fp32 out; MODE 3: gelu(acc+V+bias) bf16.
// ASRC 0: A bf16 gload_lds; ASRC 1: A fp32 reg-convert.
// BSRC 0: B fp32 reg-staged (f2bf on write); BSRC 1: B bf16 NT gload_lds;
// BSRC 2: B bf16 NN u16 scatter.
template<int MODE, int ASRC, int BSRC, int BN, int KS>
__global__ __launch_bounds__(512) void gemm_u(
    const void* __restrict__ Av, int lda,
    const void* __restrict__ Bv, int ldb,
    int N, int sliceLen, int nHalf, long long bHalfOff,
    const float* __restrict__ Vadd, const float* __restrict__ bias,
    float* __restrict__ outF, u16* __restrict__ outB,
    int ldc, int partStride)
{
    constexpr int NI = BN / 32;
    __shared__ u16 Alds[2][256 * 32];
    __shared__ u16 Blds[2][BN * 32];
    const int tid = threadIdx.x;
    const int bid = blockIdx.x;
    const int ks  = bid % KS;              // ks fastest -> same-ks blocks share an XCD
    const int nb0 = (bid / KS) * BN;
    const int mt  = blockIdx.y;
    const int k0base = ks * sliceLen;
    const int ksteps = sliceLen >> 5;
    const int lane = tid & 63, wid = tid >> 6;
    const int wm = wid >> 1, wn = wid & 1;
    const int l15 = lane & 15, kg = lane >> 4;

    const int inH2 = (nb0 >= nHalf) ? 1 : 0;
    const int nbB  = nb0 - (inH2 ? nHalf : 0);

    const u16* gA0 = nullptr; const u16* gA1 = nullptr;
    {
        int r0 = wid * 32 + (lane >> 2);
        int r1 = r0 + 16;
        int c0 = (lane & 3) ^ ((r0 >> 1) & 3);
        int c1 = (lane & 3) ^ ((r1 >> 1) & 3);
        gA0 = (const u16*)Av + (size_t)(mt * 256 + r0) * lda + k0base + c0 * 8;
        gA1 = (const u16*)Av + (size_t)(mt * 256 + r1) * lda + k0base + c1 * 8;
    }
    const int sArow = tid >> 1, sAe = (tid & 1) * 16;
    const float* ApF = (const float*)Av + (size_t)(mt * 256 + sArow) * lda + sAe + k0base;
    const int aw0 = swz(sArow, sAe >> 3);
    const int aw1 = swz(sArow, (sAe >> 3) + 1);
    float4 fa0, fa1, fa2, fa3;

    const int n2 = (tid & 31) * 2;
    const int k4 = ((tid >> 5) & 7) * 4;
    const float* BpF = (const float*)Bv + (inH2 ? (size_t)bHalfOff : 0)
                     + (size_t)(k0base + k4) * ldb + nbB + n2;
    const int bwc0 = swz(n2,     k4 >> 3) + (k4 & 4) * 2;
    const int bwc1 = swz(n2 + 1, k4 >> 3) + (k4 & 4) * 2;
    float2 Lb0, Lb1, Lb2, Lb3;
    const u16* gB0 = nullptr;
    if constexpr (BSRC == 1) {
        int tr = wid * 16 + (lane >> 2);
        int c  = (lane & 3) ^ ((tr >> 1) & 3);
        gB0 = (const u16*)Bv + (size_t)(nb0 + tr) * ldb + k0base + c * 8;
    }
    const int sBk = tid >> 4, sBn2 = (tid & 15) * 2;
    const u16* BpH = (const u16*)Bv + (size_t)(k0base + sBk) * ldb + nbB + sBn2;
    const int bh0 = swz(sBn2,     sBk >> 3) + (sBk & 7) * 2;
    const int bh1 = swz(sBn2 + 1, sBk >> 3) + (sBk & 7) * 2;
    u32 bhv = 0;

    int aoff[4], boff[NI];
    #pragma unroll
    for (int mi = 0; mi < 4; ++mi) { int r = wm * 64 + mi * 16 + l15; aoff[mi] = swz(r, kg); }
    #pragma unroll
    for (int ni = 0; ni < NI; ++ni) { int r = wn * (BN / 2) + ni * 16 + l15; boff[ni] = swz(r, kg); }

    auto stageGL = [&](int kt, int pb) {
        if constexpr (ASRC == 0) {
            char* ab = (char*)&Alds[pb][0] + wid * 2048;
            gload16(gA0 + (kt << 5), ab);
            gload16(gA1 + (kt << 5), ab + 1024);
        }
        if constexpr (BSRC == 1) {
            if (wid < BN / 16) {
                char* bb = (char*)&Blds[pb][0] + wid * 1024;
                gload16(gB0 + (kt << 5), bb);
            }
        }
    };
    auto loadA = [&](int kt) {
        const float* ap = ApF + (kt << 5);
        fa0 = *(const float4*)(ap);     fa1 = *(const float4*)(ap + 4);
        fa2 = *(const float4*)(ap + 8); fa3 = *(const float4*)(ap + 12);
    };
    auto writeA = [&](int pb) {
        char* AB = (char*)&Alds[pb][0];
        int4 w0, w1;
        w0.x = (int)((u32)f2bf(fa0.x) | ((u32)f2bf(fa0.y) << 16));
        w0.y = (int)((u32)f2bf(fa0.z) | ((u32)f2bf(fa0.w) << 16));
        w0.z = (int)((u32)f2bf(fa1.x) | ((u32)f2bf(fa1.y) << 16));
        w0.w = (int)((u32)f2bf(fa1.z) | ((u32)f2bf(fa1.w) << 16));
        w1.x = (int)((u32)f2bf(fa2.x) | ((u32)f2bf(fa2.y) << 16));
        w1.y = (int)((u32)f2bf(fa2.z) | ((u32)f2bf(fa2.w) << 16));
        w1.z = (int)((u32)f2bf(fa3.x) | ((u32)f2bf(fa3.y) << 16));
        w1.w = (int)((u32)f2bf(fa3.z) | ((u32)f2bf(fa3.w) << 16));
        *(int4*)(AB + aw0) = w0;
        *(int4*)(AB + aw1) = w1;
    };
    auto loadB = [&](int kt) {
        if constexpr (BSRC == 0) {
            if (tid < 256) {
                const float* bp = BpF + (size_t)(kt << 5) * ldb;
                Lb0 = *(const float2*)(bp);
                Lb1 = *(const float2*)(bp + ldb);
                Lb2 = *(const float2*)(bp + 2 * ldb);
                Lb3 = *(const float2*)(bp + 3 * ldb);
            }
        } else if constexpr (BSRC == 2) {
            bhv = *(const u32*)(BpH + (size_t)(kt << 5) * ldb);
        }
    };
    auto writeB = [&](int pb) {
        char* BB = (char*)&Blds[pb][0];
        if constexpr (BSRC == 0) {
            if (tid < 256) {
                uint2 p0, p1;
                p0.x = (u32)f2bf(Lb0.x) | ((u32)f2bf(Lb1.x) << 16);
                p0.y = (u32)f2bf(Lb2.x) | ((u32)f2bf(Lb3.x) << 16);
                p1.x = (u32)f2bf(Lb0.y) | ((u32)f2bf(Lb1.y) << 16);
                p1.y = (u32)f2bf(Lb2.y) | ((u32)f2bf(Lb3.y) << 16);
                *(uint2*)(BB + bwc0) = p0;
                *(uint2*)(BB + bwc1) = p1;
            }
        } else if constexpr (BSRC == 2) {
            *(u16*)(BB + bh0) = (u16)(bhv & 0xffffu);
            *(u16*)(BB + bh1) = (u16)(bhv >> 16);
        }
    };

    f32x4 acc[4][NI];
    #pragma unroll
    for (int mi = 0; mi < 4; ++mi)
        #pragma unroll
        for (int ni = 0; ni < NI; ++ni) { f32x4 zz = {0.f, 0.f, 0.f, 0.f}; acc[mi][ni] = zz; }

    auto mfmaStep = [&](int pb) {
        const char* AB = (const char*)&Alds[pb][0];
        const char* BB = (const char*)&Blds[pb][0];
        bf16x8 af[4], bfr[NI];
        #pragma unroll
        for (int mi = 0; mi < 4; ++mi) af[mi] = *(const bf16x8*)(AB + aoff[mi]);
        #pragma unroll
        for (int ni = 0; ni < NI; ++ni) bfr[ni] = *(const bf16x8*)(BB + boff[ni]);
        #pragma unroll
        for (int mi = 0; mi < 4; ++mi)
            #pragma unroll
            for (int ni = 0; ni < NI; ++ni)
                acc[mi][ni] = __builtin_amdgcn_mfma_f32_16x16x32_bf16(af[mi], bfr[ni], acc[mi][ni], 0, 0, 0);
    };

    stageGL(0, 0);
    if constexpr (ASRC == 1) { loadA(0); writeA(0); loadA(1); }
    if constexpr (BSRC == 0 || BSRC == 2) { loadB(0); writeB(0); loadB(1); }
    __syncthreads();
    for (int kt = 0; kt < ksteps; ++kt) {
        const int pb = kt & 1;
        if (kt + 1 < ksteps) {
            stageGL(kt + 1, pb ^ 1);
            if constexpr (ASRC == 1) writeA(pb ^ 1);
            if constexpr (BSRC == 0 || BSRC == 2) writeB(pb ^ 1);
        }
        if (kt + 2 < ksteps) {
            if constexpr (ASRC == 1) loadA(kt + 2);
            if constexpr (BSRC == 0 || BSRC == 2) loadB(kt + 2);
        }
        mfmaStep(pb);
        __syncthreads();
    }

    const int rq = lane >> 4;
    #pragma unroll
    for (int mi = 0; mi < 4; ++mi)
        #pragma unroll
        for (int ni = 0; ni < NI; ++ni)
            #pragma unroll
            for (int r = 0; r < 4; ++r) {
                int m = wm * 64 + mi * 16 + rq * 4 + r;
                int n = nb0 + wn * (BN / 2) + ni * 16 + l15;
                float v = acc[mi][ni][r];
                if (MODE == 0)
                    outB[(size_t)ks * partStride + (size_t)m * N + n] = f2bf(v);
                else if (MODE == 2)
                    outF[(size_t)(mt * 256 + m) * ldc + n] = v;
                else {
                    float h = geluf(v + Vadd[(size_t)m * N + n] + bias[n]);
                    outB[(size_t)m * ldc + n] = f2bf(h);
                }
            }
}

// -------- sum 64 bf16 cov partials -> covbf ------------------------------------
__global__ __launch_bounds__(256) void reduce_cov(const u16* __restrict__ parts,
                                                  u16* __restrict__ out) {
    int i8 = (blockIdx.x * 256 + threadIdx.x) * 8;   // grid 32 -> 65536
    float s[8] = {};
    #pragma unroll
    for (int sl = 0; sl < 64; ++sl) {
        uint4 v = *(const uint4*)(parts + (size_t)sl * 65536 + i8);
        u32 w[4] = {v.x, v.y, v.z, v.w};
        #pragma unroll
        for (int j = 0; j < 4; ++j) {
            union { u32 u; float f; } lo, hi;
            lo.u = (w[j] & 0xffffu) << 16; hi.u = w[j] & 0xffff0000u;
            s[2 * j] += lo.f; s[2 * j + 1] += hi.f;
        }
    }
    uint4 pk;
    pk.x = (u32)f2bf(s[0]) | ((u32)f2bf(s[1]) << 16);
    pk.y = (u32)f2bf(s[2]) | ((u32)f2bf(s[3]) << 16);
    pk.z = (u32)f2bf(s[4]) | ((u32)f2bf(s[5]) << 16);
    pk.w = (u32)f2bf(s[6]) | ((u32)f2bf(s[7]) << 16);
    *(uint4*)(out + i8) = pk;
}

// -------- fc1 partials (16 slices of 256x8192) -> V fp32 (n<4096) / Ubf (n>=4096)
__global__ __launch_bounds__(256) void reduce_vu(const u16* __restrict__ parts,
                                                 float* __restrict__ V,
                                                 u16* __restrict__ U) {
    int i8 = (blockIdx.x * 256 + threadIdx.x) * 8;   // grid 1024 -> 2M
    int m = i8 >> 13, n = i8 & 8191;
    float s[8] = {};
    #pragma unroll
    for (int sl = 0; sl < 16; ++sl) {
        uint4 v = *(const uint4*)(parts + (size_t)sl * (256 * 8192) + i8);
        u32 w[4] = {v.x, v.y, v.z, v.w};
        #pragma unroll
        for (int j = 0; j < 4; ++j) {
            union { u32 u; float f; } lo, hi;
            lo.u = (w[j] & 0xffffu) << 16; hi.u = w[j] & 0xffff0000u;
            s[2 * j] += lo.f; s[2 * j + 1] += hi.f;
        }
    }
    if (n < 4096) {
        float* vp = V + (size_t)m * 4096 + n;
        *(float4*)(vp)     = make_float4(s[0], s[1], s[2], s[3]);
        *(float4*)(vp + 4) = make_float4(s[4], s[5], s[6], s[7]);
    } else {
        uint4 pk;
        pk.x = (u32)f2bf(s[0]) | ((u32)f2bf(s[1]) << 16);
        pk.y = (u32)f2bf(s[2]) | ((u32)f2bf(s[3]) << 16);
        pk.z = (u32)f2bf(s[4]) | ((u32)f2bf(s[5]) << 16);
        pk.w = (u32)f2bf(s[6]) | ((u32)f2bf(s[7]) << 16);
        *(uint4*)(U + (size_t)m * 4096 + (n - 4096)) = pk;
    }
}

// -------- fc2 partials (32 slices) + bias + gelu -> of32 fp32 ------------------
__global__ __launch_bounds__(256) void reduce_fc32(const u16* __restrict__ parts,
                                                   const float* __restrict__ bias,
                                                   float* __restrict__ outF) {
    int i8 = (blockIdx.x * 256 + threadIdx.x) * 8;   // grid 256 -> 512K
    int col = i8 & (Y1D - 1);
    float s[8] = {};
    #pragma unroll
    for (int sl = 0; sl < 32; ++sl) {
        uint4 v = *(const uint4*)(parts + (size_t)sl * (256 * Y1D) + i8);
        u32 w[4] = {v.x, v.y, v.z, v.w};
        #pragma unroll
        for (int j = 0; j < 4; ++j) {
            union { u32 u; float f; } lo, hi;
            lo.u = (w[j] & 0xffffu) << 16; hi.u = w[j] & 0xffff0000u;
            s[2 * j] += lo.f; s[2 * j + 1] += hi.f;
        }
    }
    float4 b0 = *(const float4*)(bias + col);
    float4 b1 = *(const float4*)(bias + col + 4);
    s[0] = geluf(s[0] + b0.x); s[1] = geluf(s[1] + b0.y);
    s[2] = geluf(s[2] + b0.z); s[3] = geluf(s[3] + b0.w);
    s[4] = geluf(s[4] + b1.x); s[5] = geluf(s[5] + b1.y);
    s[6] = geluf(s[6] + b1.z); s[7] = geluf(s[7] + b1.w);
    *(float4*)(outF + i8)     = make_float4(s[0], s[1], s[2], s[3]);
    *(float4*)(outF + i8 + 4) = make_float4(s[4], s[5], s[6], s[7]);
}

extern "C" void kernel_launch(void* const* d_in, const int* in_sizes, int n_in,
                              void* d_out, int out_size, void* d_ws, size_t ws_size,
                              hipStream_t stream) {
    const float* X     = (const float*)d_in[0];
    const float* wn_w1 = (const float*)d_in[1];
    const float* wn_b1 = (const float*)d_in[2];
    const float* wn_w2 = (const float*)d_in[3];
    const float* wn_b2 = (const float*)d_in[4];
    const float* fc1_w = (const float*)d_in[5];
    const float* fc1_b = (const float*)d_in[6];
    const float* fc2_w = (const float*)d_in[7];
    const float* fc2_b = (const float*)d_in[8];
    const float* proj  = (const float*)d_in[9];

    char* ws = (char*)d_ws;
    size_t off = 0;
    auto alloc = [&](size_t bytes) { size_t o = off; off += (bytes + 255) & ~(size_t)255; return o; };
    u16*   Zb    = (u16*)  (ws + alloc((size_t)C_DIM * D_DIM * 2));
    u16*   Xob   = (u16*)  (ws + alloc((size_t)C_DIM * D_DIM * 2));
    u16*   Xb    = (u16*)  (ws + alloc((size_t)C_DIM * D_DIM * 2));
    u16*   covp  = (u16*)  (ws + alloc((size_t)64 * 65536 * 2));
    u16*   covbf = (u16*)  (ws + alloc((size_t)65536 * 2));
    u16*   p1b   = (u16*)  (ws + alloc((size_t)16 * C_DIM * D_DIM * 2));
    float* Vf    = (float*)(ws + alloc((size_t)C_DIM * HIDD * 4));
    u16*   Ubf   = (u16*)  (ws + alloc((size_t)C_DIM * HIDD * 2));
    u16*   hbf   = (u16*)  (ws + alloc((size_t)C_DIM * HIDD * 2));
    u16*   p2b   = (u16*)  (ws + alloc((size_t)32 * C_DIM * Y1D * 2));
    float* of32  = (float*)(ws + alloc((size_t)C_DIM * Y1D * 4));

    filterk<<<C_DIM, 256, 0, stream>>>(X, wn_w1, wn_b1, wn_w2, wn_b2, Zb, Xob, Xb);
    // cov partials: Zb @ Xob^T (A+B gload_lds), KS=64 -> 256 blocks (1/CU)
    gemm_u<0, 0, 1, 64, 64><<<256, 512, 0, stream>>>(Zb, D_DIM, Xob, D_DIM,
        C_DIM, D_DIM / 64, C_DIM, 0, nullptr, nullptr, nullptr, covp, 0, 65536);
    reduce_cov<<<32, 256, 0, stream>>>(covp, covbf);
    // fc1 fused: Xb @ [W_top | W_bot], KS=16 -> 2048 blocks (4 resident/CU)
    gemm_u<0, 0, 0, 64, 16><<<(2 * HIDD / 64) * 16, 512, 0, stream>>>(Xb, D_DIM, fc1_w, HIDD,
        2 * HIDD, D_DIM / 16, HIDD, (long long)D_DIM * HIDD, nullptr, nullptr,
        nullptr, p1b, 0, C_DIM * 2 * HIDD);
    reduce_vu<<<1024, 256, 0, stream>>>(p1b, Vf, Ubf);
    // h = gelu(V + cov @ U + b1)  (K=256, A gload, B bf16 NN)
    gemm_u<3, 0, 2, 32, 1><<<HIDD / 32, 512, 0, stream>>>(covbf, C_DIM, Ubf, HIDD,
        HIDD, C_DIM, HIDD, 0, Vf, fc1_b, nullptr, hbf, HIDD, 0);
    // fc2: h @ fc2_w, KS=32 -> 1024 blocks (4 resident/CU)
    gemm_u<0, 0, 0, 64, 32><<<(Y1D / 64) * 32, 512, 0, stream>>>(hbf, HIDD, fc2_w, Y1D,
        Y1D, HIDD / 32, 1 << 30, 0, nullptr, nullptr, nullptr, p2b, 0, C_DIM * Y1D);
    reduce_fc32<<<C_DIM * Y1D / 8 / 256, 256, 0, stream>>>(p2b, fc2_b, of32);
    // out = proj @ o   (A fp32 reg-convert; M=512 -> 2 m-tiles)
    gemm_u<2, 1, 0, 64, 1><<<dim3(Y1D / 64, 2), 512, 0, stream>>>(proj, C_DIM, of32, Y1D,
        Y1D, C_DIM, Y1D, 0, nullptr, nullptr, (float*)d_out, nullptr, Y1D, 0);
}

// Round 17
// 180.798 us; speedup vs baseline: 1.6915x; 1.2474x over previous
//
#include <hip/hip_runtime.h>
#include <math.h>

typedef unsigned short u16;
typedef unsigned int   u32;

typedef __bf16 bf16x8 __attribute__((ext_vector_type(8)));
typedef float  f32x4  __attribute__((ext_vector_type(4)));

#define C_DIM 256
#define D_DIM 8192
#define HIDD  4096
#define Y1D   2048

__device__ __forceinline__ u16 f2bf(float f) {
    union { float f; u32 u; } v; v.f = f;
    u32 r = v.u + 0x7fffu + ((v.u >> 16) & 1u);   // RNE
    return (u16)(r >> 16);
}
__device__ __forceinline__ float geluf(float x) {
    return 0.5f * x * (1.0f + erff(x * 0.70710678118654752f));
}
// LDS swizzle: 16B chunk kg within a 64B row, XOR'd by row bits -> low-conflict reads
__device__ __forceinline__ int swz(int row, int kg) {
    return row * 64 + (((kg) ^ ((row >> 1) & 3)) << 4);
}
// fp32 LDS swizzle for the filter row buffer
__device__ __forceinline__ int xsw(int t) {
    int ch = t >> 2;
    return (((ch ^ ((ch >> 3) & 7))) << 2) | (t & 3);
}
// async global->LDS, 16B per lane; lds dest wave-uniform base (lane*16 implicit)
__device__ __forceinline__ void gload16(const void* g, void* l) {
    __builtin_amdgcn_global_load_lds(
        (const __attribute__((address_space(1))) void*)g,
        (__attribute__((address_space(3))) void*)l, 16, 0, 0);
}

// ---- per-row: weight-net coefs (fused), Z=FIR(c,X-mu) bf16, Xo bf16, X bf16 ----
__global__ __launch_bounds__(256) void filterk(const float* __restrict__ X,
                                               const float* __restrict__ w1,
                                               const float* __restrict__ b1,
                                               const float* __restrict__ w2,
                                               const float* __restrict__ b2,
                                               u16* __restrict__ Zb,
                                               u16* __restrict__ Xob,
                                               u16* __restrict__ Xb) {
    __shared__ float Xl[8240];
    __shared__ float wl[65];
    __shared__ float cl[40];
    __shared__ float red[4];
    int i = blockIdx.x, tid = threadIdx.x;
    int lane = tid & 63, wv = tid >> 6;
    const float* row = X + (size_t)i * D_DIM;
    float s = 0.f;
    #pragma unroll
    for (int q = 0; q < 8; ++q) {
        int t = tid * 32 + q * 4;
        float4 v = *(const float4*)(row + t);
        s += v.x + v.y + v.z + v.w;
        *(float4*)(Xl + xsw(t)) = v;
    }
    float w1l = w1[lane], b1l = b1[lane], w2l = w2[lane], b2l = b2[0];
    for (int li = wv; li < 65; li += 4) {
        float lag = (float)(li - 32);
        float h = geluf(lag * w1l + b1l);
        float p = h * w2l;
        #pragma unroll
        for (int off = 32; off; off >>= 1) p += __shfl_xor(p, off);
        if (lane == 0) wl[li] = p + b2l;
    }
    #pragma unroll
    for (int off = 32; off; off >>= 1) s += __shfl_xor(s, off);
    if (lane == 0) red[wv] = s;
    __syncthreads();
    if (tid <= 32) {
        cl[tid] = (tid == 0) ? wl[32] / (float)D_DIM
                             : (wl[32 - tid] + wl[32 + tid]) / ((float)D_DIM - (float)tid);
    }
    if (tid == 33) {
        float ssum = wl[32] / (float)D_DIM;
        for (int k = 1; k <= 32; ++k) ssum += (wl[32 - k] + wl[32 + k]) / ((float)D_DIM - (float)k);
        cl[33] = ssum;
    }
    float mu = (red[0] + red[1] + red[2] + red[3]) * (1.f / (float)D_DIM);
    if (tid < 10) {
        float4 mv = make_float4(mu, mu, mu, mu);
        *(float4*)(Xl + xsw(D_DIM + tid * 4)) = mv;
    }
    __syncthreads();
    float csum = cl[33];
    #pragma unroll
    for (int ch = 0; ch < 8; ++ch) {
        int t4 = tid * 32 + ch * 4;
        float w[40] __attribute__((aligned(16)));
        #pragma unroll
        for (int g = 0; g < 10; ++g)
            *(float4*)(w + g * 4) = *(const float4*)(Xl + xsw(t4 + g * 4));
        u16 zb[4], xo[4], xb[4];
        #pragma unroll
        for (int j = 0; j < 4; ++j) {
            float a = 0.f;
            #pragma unroll
            for (int k = 0; k < 33; ++k) a = fmaf(cl[k], w[j + k], a);
            zb[j] = f2bf(a - mu * csum);
            xo[j] = f2bf(w[j] - mu);
            xb[j] = f2bf(w[j]);
        }
        uint2 zp, op, bp;
        zp.x = (u32)zb[0] | ((u32)zb[1] << 16); zp.y = (u32)zb[2] | ((u32)zb[3] << 16);
        op.x = (u32)xo[0] | ((u32)xo[1] << 16); op.y = (u32)xo[2] | ((u32)xo[3] << 16);
        bp.x = (u32)xb[0] | ((u32)xb[1] << 16); bp.y = (u32)xb[2] | ((u32)xb[3] << 16);
        *(uint2*)(Zb  + (size_t)i * D_DIM + t4) = zp;
        *(uint2*)(Xob + (size_t)i * D_DIM + t4) = op;
        *(uint2*)(Xb  + (size_t)i * D_DIM + t4) = bp;
    }
}

// ------- unified bf16 MFMA GEMM (R12-proven sync structure) --------------------
// MODE 0: bf16 split-K partials; MODE 2: fp32 out; MODE 3: gelu(acc+V+bias) bf16.
// ASRC 0: A bf16 gload_lds; ASRC 1: A fp32 reg-convert.
// BSRC 0: B fp32, 2n x 4k/thread (BN=64); BSRC 1: B bf16 NT gload_lds;
// BSRC 2: B bf16 NN u16 scatter; BSRC 3: B fp32, 8k x 1n/thread -> ds_write_b128
//         (BN=128: 512B-contiguous DRAM runs per k-row, one b128 LDS write).
template<int MODE, int ASRC, int BSRC, int BN, int KS>
__global__ __launch_bounds__(512) void gemm_u(
    const void* __restrict__ Av, int lda,
    const void* __restrict__ Bv, int ldb,
    int N, int sliceLen, int nHalf, long long bHalfOff,
    const float* __restrict__ Vadd, const float* __restrict__ bias,
    float* __restrict__ outF, u16* __restrict__ outB,
    int ldc, int partStride)
{
    constexpr int NI = BN / 32;
    __shared__ u16 Alds[2][256 * 32];
    __shared__ u16 Blds[2][BN * 32];
    const int tid = threadIdx.x;
    const int bid = blockIdx.x;
    const int ks  = bid % KS;              // ks fastest -> same-ks blocks share an XCD
    const int nb0 = (bid / KS) * BN;
    const int mt  = blockIdx.y;
    const int k0base = ks * sliceLen;
    const int ksteps = sliceLen >> 5;
    const int lane = tid & 63, wid = tid >> 6;
    const int wm = wid >> 1, wn = wid & 1;
    const int l15 = lane & 15, kg = lane >> 4;

    const int inH2 = (nb0 >= nHalf) ? 1 : 0;
    const int nbB  = nb0 - (inH2 ? nHalf : 0);

    const u16* gA0 = nullptr; const u16* gA1 = nullptr;
    {
        int r0 = wid * 32 + (lane >> 2);
        int r1 = r0 + 16;
        int c0 = (lane & 3) ^ ((r0 >> 1) & 3);
        int c1 = (lane & 3) ^ ((r1 >> 1) & 3);
        gA0 = (const u16*)Av + (size_t)(mt * 256 + r0) * lda + k0base + c0 * 8;
        gA1 = (const u16*)Av + (size_t)(mt * 256 + r1) * lda + k0base + c1 * 8;
    }
    const int sArow = tid >> 1, sAe = (tid & 1) * 16;
    const float* ApF = (const float*)Av + (size_t)(mt * 256 + sArow) * lda + sAe + k0base;
    const int aw0 = swz(sArow, sAe >> 3);
    const int aw1 = swz(sArow, (sAe >> 3) + 1);
    float4 fa0, fa1, fa2, fa3;

    // BSRC 0 (BN=64): thread covers 2n x 4k
    const int n2 = (tid & 31) * 2;
    const int k4 = ((tid >> 5) & 7) * 4;
    const float* BpF = (const float*)Bv + (inH2 ? (size_t)bHalfOff : 0)
                     + (size_t)(k0base + k4) * ldb + nbB + n2;
    const int bwc0 = swz(n2,     k4 >> 3) + (k4 & 4) * 2;
    const int bwc1 = swz(n2 + 1, k4 >> 3) + (k4 & 4) * 2;
    float2 Lb0, Lb1, Lb2, Lb3;
    // BSRC 1: bf16 NT gload
    const u16* gB0 = nullptr;
    if constexpr (BSRC == 1) {
        int tr = wid * 16 + (lane >> 2);
        int c  = (lane & 3) ^ ((tr >> 1) & 3);
        gB0 = (const u16*)Bv + (size_t)(nb0 + tr) * ldb + k0base + c * 8;
    }
    // BSRC 2: bf16 NN scatter
    const int sBk = tid >> 4, sBn2 = (tid & 15) * 2;
    const u16* BpH = (const u16*)Bv + (size_t)(k0base + sBk) * ldb + nbB + sBn2;
    const int bh0 = swz(sBn2,     sBk >> 3) + (sBk & 7) * 2;
    const int bh1 = swz(sBn2 + 1, sBk >> 3) + (sBk & 7) * 2;
    u32 bhv = 0;
    // BSRC 3 (BN=128): thread covers 8k x 1n; one b128 LDS write
    const int b3n = tid & 127;
    const int b3k = (tid >> 7) * 8;
    const float* Bp3 = (const float*)Bv + (inH2 ? (size_t)bHalfOff : 0)
                     + (size_t)(k0base + b3k) * ldb + nbB + b3n;
    const int bw3 = swz(b3n, b3k >> 3);
    float b3v[8];

    int aoff[4], boff[NI];
    #pragma unroll
    for (int mi = 0; mi < 4; ++mi) { int r = wm * 64 + mi * 16 + l15; aoff[mi] = swz(r, kg); }
    #pragma unroll
    for (int ni = 0; ni < NI; ++ni) { int r = wn * (BN / 2) + ni * 16 + l15; boff[ni] = swz(r, kg); }

    auto stageGL = [&](int kt, int pb) {
        if constexpr (ASRC == 0) {
            char* ab = (char*)&Alds[pb][0] + wid * 2048;
            gload16(gA0 + (kt << 5), ab);
            gload16(gA1 + (kt << 5), ab + 1024);
        }
        if constexpr (BSRC == 1) {
            if (wid < BN / 16) {
                char* bb = (char*)&Blds[pb][0] + wid * 1024;
                gload16(gB0 + (kt << 5), bb);
            }
        }
    };
    auto loadA = [&](int kt) {
        const float* ap = ApF + (kt << 5);
        fa0 = *(const float4*)(ap);     fa1 = *(const float4*)(ap + 4);
        fa2 = *(const float4*)(ap + 8); fa3 = *(const float4*)(ap + 12);
    };
    auto writeA = [&](int pb) {
        char* AB = (char*)&Alds[pb][0];
        int4 w0, w1;
        w0.x = (int)((u32)f2bf(fa0.x) | ((u32)f2bf(fa0.y) << 16));
        w0.y = (int)((u32)f2bf(fa0.z) | ((u32)f2bf(fa0.w) << 16));
        w0.z = (int)((u32)f2bf(fa1.x) | ((u32)f2bf(fa1.y) << 16));
        w0.w = (int)((u32)f2bf(fa1.z) | ((u32)f2bf(fa1.w) << 16));
        w1.x = (int)((u32)f2bf(fa2.x) | ((u32)f2bf(fa2.y) << 16));
        w1.y = (int)((u32)f2bf(fa2.z) | ((u32)f2bf(fa2.w) << 16));
        w1.z = (int)((u32)f2bf(fa3.x) | ((u32)f2bf(fa3.y) << 16));
        w1.w = (int)((u32)f2bf(fa3.z) | ((u32)f2bf(fa3.w) << 16));
        *(int4*)(AB + aw0) = w0;
        *(int4*)(AB + aw1) = w1;
    };
    auto loadB = [&](int kt) {
        if constexpr (BSRC == 0) {
            if (tid < 256) {
                const float* bp = BpF + (size_t)(kt << 5) * ldb;
                Lb0 = *(const float2*)(bp);
                Lb1 = *(const float2*)(bp + ldb);
                Lb2 = *(const float2*)(bp + 2 * ldb);
                Lb3 = *(const float2*)(bp + 3 * ldb);
            }
        } else if constexpr (BSRC == 2) {
            bhv = *(const u32*)(BpH + (size_t)(kt << 5) * ldb);
        } else if constexpr (BSRC == 3) {
            const float* bp = Bp3 + (size_t)(kt << 5) * ldb;
            #pragma unroll
            for (int j = 0; j < 8; ++j) b3v[j] = bp[(size_t)j * ldb];
        }
    };
    auto writeB = [&](int pb) {
        char* BB = (char*)&Blds[pb][0];
        if constexpr (BSRC == 0) {
            if (tid < 256) {
                uint2 p0, p1;
                p0.x = (u32)f2bf(Lb0.x) | ((u32)f2bf(Lb1.x) << 16);
                p0.y = (u32)f2bf(Lb2.x) | ((u32)f2bf(Lb3.x) << 16);
                p1.x = (u32)f2bf(Lb0.y) | ((u32)f2bf(Lb1.y) << 16);
                p1.y = (u32)f2bf(Lb2.y) | ((u32)f2bf(Lb3.y) << 16);
                *(uint2*)(BB + bwc0) = p0;
                *(uint2*)(BB + bwc1) = p1;
            }
        } else if constexpr (BSRC == 2) {
            *(u16*)(BB + bh0) = (u16)(bhv & 0xffffu);
            *(u16*)(BB + bh1) = (u16)(bhv >> 16);
        } else if constexpr (BSRC == 3) {
            uint4 p;
            p.x = (u32)f2bf(b3v[0]) | ((u32)f2bf(b3v[1]) << 16);
            p.y = (u32)f2bf(b3v[2]) | ((u32)f2bf(b3v[3]) << 16);
            p.z = (u32)f2bf(b3v[4]) | ((u32)f2bf(b3v[5]) << 16);
            p.w = (u32)f2bf(b3v[6]) | ((u32)f2bf(b3v[7]) << 16);
            *(uint4*)(BB + bw3) = p;
        }
    };

    f32x4 acc[4][NI];
    #pragma unroll
    for (int mi = 0; mi < 4; ++mi)
        #pragma unroll
        for (int ni = 0; ni < NI; ++ni) { f32x4 zz = {0.f, 0.f, 0.f, 0.f}; acc[mi][ni] = zz; }

    auto mfmaStep = [&](int pb) {
        const char* AB = (const char*)&Alds[pb][0];
        const char* BB = (const char*)&Blds[pb][0];
        bf16x8 af[4], bfr[NI];
        #pragma unroll
        for (int mi = 0; mi < 4; ++mi) af[mi] = *(const bf16x8*)(AB + aoff[mi]);
        #pragma unroll
        for (int ni = 0; ni < NI; ++ni) bfr[ni] = *(const bf16x8*)(BB + boff[ni]);
        #pragma unroll
        for (int mi = 0; mi < 4; ++mi)
            #pragma unroll
            for (int ni = 0; ni < NI; ++ni)
                acc[mi][ni] = __builtin_amdgcn_mfma_f32_16x16x32_bf16(af[mi], bfr[ni], acc[mi][ni], 0, 0, 0);
    };

    stageGL(0, 0);
    if constexpr (ASRC == 1) { loadA(0); writeA(0); loadA(1); }
    if constexpr (BSRC == 0 || BSRC == 2 || BSRC == 3) { loadB(0); writeB(0); loadB(1); }
    __syncthreads();
    for (int kt = 0; kt < ksteps; ++kt) {
        const int pb = kt & 1;
        if (kt + 1 < ksteps) {
            stageGL(kt + 1, pb ^ 1);
            if constexpr (ASRC == 1) writeA(pb ^ 1);
            if constexpr (BSRC == 0 || BSRC == 2 || BSRC == 3) writeB(pb ^ 1);
        }
        if (kt + 2 < ksteps) {
            if constexpr (ASRC == 1) loadA(kt + 2);
            if constexpr (BSRC == 0 || BSRC == 2 || BSRC == 3) loadB(kt + 2);
        }
        mfmaStep(pb);
        __syncthreads();
    }

    const int rq = lane >> 4;
    #pragma unroll
    for (int mi = 0; mi < 4; ++mi)
        #pragma unroll
        for (int ni = 0; ni < NI; ++ni)
            #pragma unroll
            for (int r = 0; r < 4; ++r) {
                int m = wm * 64 + mi * 16 + rq * 4 + r;
                int n = nb0 + wn * (BN / 2) + ni * 16 + l15;
                float v = acc[mi][ni][r];
                if (MODE == 0)
                    outB[(size_t)ks * partStride + (size_t)m * N + n] = f2bf(v);
                else if (MODE == 2)
                    outF[(size_t)(mt * 256 + m) * ldc + n] = v;
                else {
                    float h = geluf(v + Vadd[(size_t)m * N + n] + bias[n]);
                    outB[(size_t)m * ldc + n] = f2bf(h);
                }
            }
}

// -------- sum 32 bf16 cov partials -> covbf ------------------------------------
__global__ __launch_bounds__(256) void reduce_cov(const u16* __restrict__ parts,
                                                  u16* __restrict__ out) {
    int i8 = (blockIdx.x * 256 + threadIdx.x) * 8;   // grid 32 -> 65536
    float s[8] = {};
    #pragma unroll
    for (int sl = 0; sl < 32; ++sl) {
        uint4 v = *(const uint4*)(parts + (size_t)sl * 65536 + i8);
        u32 w[4] = {v.x, v.y, v.z, v.w};
        #pragma unroll
        for (int j = 0; j < 4; ++j) {
            union { u32 u; float f; } lo, hi;
            lo.u = (w[j] & 0xffffu) << 16; hi.u = w[j] & 0xffff0000u;
            s[2 * j] += lo.f; s[2 * j + 1] += hi.f;
        }
    }
    uint4 pk;
    pk.x = (u32)f2bf(s[0]) | ((u32)f2bf(s[1]) << 16);
    pk.y = (u32)f2bf(s[2]) | ((u32)f2bf(s[3]) << 16);
    pk.z = (u32)f2bf(s[4]) | ((u32)f2bf(s[5]) << 16);
    pk.w = (u32)f2bf(s[6]) | ((u32)f2bf(s[7]) << 16);
    *(uint4*)(out + i8) = pk;
}

// -------- fc1 partials (16 slices of 256x8192) -> V fp32 (n<4096) / Ubf (n>=4096)
__global__ __launch_bounds__(256) void reduce_vu(const u16* __restrict__ parts,
                                                 float* __restrict__ V,
                                                 u16* __restrict__ U) {
    int i8 = (blockIdx.x * 256 + threadIdx.x) * 8;   // grid 1024 -> 2M
    int m = i8 >> 13, n = i8 & 8191;
    float s[8] = {};
    #pragma unroll
    for (int sl = 0; sl < 16; ++sl) {
        uint4 v = *(const uint4*)(parts + (size_t)sl * (256 * 8192) + i8);
        u32 w[4] = {v.x, v.y, v.z, v.w};
        #pragma unroll
        for (int j = 0; j < 4; ++j) {
            union { u32 u; float f; } lo, hi;
            lo.u = (w[j] & 0xffffu) << 16; hi.u = w[j] & 0xffff0000u;
            s[2 * j] += lo.f; s[2 * j + 1] += hi.f;
        }
    }
    if (n < 4096) {
        float* vp = V + (size_t)m * 4096 + n;
        *(float4*)(vp)     = make_float4(s[0], s[1], s[2], s[3]);
        *(float4*)(vp + 4) = make_float4(s[4], s[5], s[6], s[7]);
    } else {
        uint4 pk;
        pk.x = (u32)f2bf(s[0]) | ((u32)f2bf(s[1]) << 16);
        pk.y = (u32)f2bf(s[2]) | ((u32)f2bf(s[3]) << 16);
        pk.z = (u32)f2bf(s[4]) | ((u32)f2bf(s[5]) << 16);
        pk.w = (u32)f2bf(s[6]) | ((u32)f2bf(s[7]) << 16);
        *(uint4*)(U + (size_t)m * 4096 + (n - 4096)) = pk;
    }
}

// -------- fc2 partials (32 slices) + bias + gelu -> of32 fp32 ------------------
__global__ __launch_bounds__(256) void reduce_fc32(const u16* __restrict__ parts,
                                                   const float* __restrict__ bias,
                                                   float* __restrict__ outF) {
    int i8 = (blockIdx.x * 256 + threadIdx.x) * 8;   // grid 256 -> 512K
    int col = i8 & (Y1D - 1);
    float s[8] = {};
    #pragma unroll
    for (int sl = 0; sl < 32; ++sl) {
        uint4 v = *(const uint4*)(parts + (size_t)sl * (256 * Y1D) + i8);
        u32 w[4] = {v.x, v.y, v.z, v.w};
        #pragma unroll
        for (int j = 0; j < 4; ++j) {
            union { u32 u; float f; } lo, hi;
            lo.u = (w[j] & 0xffffu) << 16; hi.u = w[j] & 0xffff0000u;
            s[2 * j] += lo.f; s[2 * j + 1] += hi.f;
        }
    }
    float4 b0 = *(const float4*)(bias + col);
    float4 b1 = *(const float4*)(bias + col + 4);
    s[0] = geluf(s[0] + b0.x); s[1] = geluf(s[1] + b0.y);
    s[2] = geluf(s[2] + b0.z); s[3] = geluf(s[3] + b0.w);
    s[4] = geluf(s[4] + b1.x); s[5] = geluf(s[5] + b1.y);
    s[6] = geluf(s[6] + b1.z); s[7] = geluf(s[7] + b1.w);
    *(float4*)(outF + i8)     = make_float4(s[0], s[1], s[2], s[3]);
    *(float4*)(outF + i8 + 4) = make_float4(s[4], s[5], s[6], s[7]);
}

extern "C" void kernel_launch(void* const* d_in, const int* in_sizes, int n_in,
                              void* d_out, int out_size, void* d_ws, size_t ws_size,
                              hipStream_t stream) {
    const float* X     = (const float*)d_in[0];
    const float* wn_w1 = (const float*)d_in[1];
    const float* wn_b1 = (const float*)d_in[2];
    const float* wn_w2 = (const float*)d_in[3];
    const float* wn_b2 = (const float*)d_in[4];
    const float* fc1_w = (const float*)d_in[5];
    const float* fc1_b = (const float*)d_in[6];
    const float* fc2_w = (const float*)d_in[7];
    const float* fc2_b = (const float*)d_in[8];
    const float* proj  = (const float*)d_in[9];

    char* ws = (char*)d_ws;
    size_t off = 0;
    auto alloc = [&](size_t bytes) { size_t o = off; off += (bytes + 255) & ~(size_t)255; return o; };
    u16*   Zb    = (u16*)  (ws + alloc((size_t)C_DIM * D_DIM * 2));
    u16*   Xob   = (u16*)  (ws + alloc((size_t)C_DIM * D_DIM * 2));
    u16*   Xb    = (u16*)  (ws + alloc((size_t)C_DIM * D_DIM * 2));
    u16*   covp  = (u16*)  (ws + alloc((size_t)32 * 65536 * 2));
    u16*   covbf = (u16*)  (ws + alloc((size_t)65536 * 2));
    u16*   p1b   = (u16*)  (ws + alloc((size_t)16 * C_DIM * D_DIM * 2));
    float* Vf    = (float*)(ws + alloc((size_t)C_DIM * HIDD * 4));
    u16*   Ubf   = (u16*)  (ws + alloc((size_t)C_DIM * HIDD * 2));
    u16*   hbf   = (u16*)  (ws + alloc((size_t)C_DIM * HIDD * 2));
    u16*   p2b   = (u16*)  (ws + alloc((size_t)32 * C_DIM * Y1D * 2));
    float* of32  = (float*)(ws + alloc((size_t)C_DIM * Y1D * 4));

    filterk<<<C_DIM, 256, 0, stream>>>(X, wn_w1, wn_b1, wn_w2, wn_b2, Zb, Xob, Xb);
    // cov partials: Zb @ Xob^T (A+B gload_lds), KS=32 -> 128 blocks (R12 proven)
    gemm_u<0, 0, 1, 64, 32><<<128, 512, 0, stream>>>(Zb, D_DIM, Xob, D_DIM,
        C_DIM, D_DIM / 32, C_DIM, 0, nullptr, nullptr, nullptr, covp, 0, 65536);
    reduce_cov<<<32, 256, 0, stream>>>(covp, covbf);
    // fc1 fused: Xb @ [W_top | W_bot], BN=128/KS=16 -> 1024 blocks, 3 resident/CU
    gemm_u<0, 0, 3, 128, 16><<<(2 * HIDD / 128) * 16, 512, 0, stream>>>(Xb, D_DIM, fc1_w, HIDD,
        2 * HIDD, D_DIM / 16, HIDD, (long long)D_DIM * HIDD, nullptr, nullptr,
        nullptr, p1b, 0, C_DIM * 2 * HIDD);
    reduce_vu<<<1024, 256, 0, stream>>>(p1b, Vf, Ubf);
    // h = gelu(V + cov @ U + b1)  (K=256, A gload, B bf16 NN)
    gemm_u<3, 0, 2, 32, 1><<<HIDD / 32, 512, 0, stream>>>(covbf, C_DIM, Ubf, HIDD,
        HIDD, C_DIM, HIDD, 0, Vf, fc1_b, nullptr, hbf, HIDD, 0);
    // fc2: h @ fc2_w, BN=128/KS=32 -> 512 blocks (ksteps=4)
    gemm_u<0, 0, 3, 128, 32><<<(Y1D / 128) * 32, 512, 0, stream>>>(hbf, HIDD, fc2_w, Y1D,
        Y1D, HIDD / 32, 1 << 30, 0, nullptr, nullptr, nullptr, p2b, 0, C_DIM * Y1D);
    reduce_fc32<<<C_DIM * Y1D / 8 / 256, 256, 0, stream>>>(p2b, fc2_b, of32);
    // out = proj @ o   (A fp32 reg-convert; M=512 -> 2 m-tiles)
    gemm_u<2, 1, 0, 64, 1><<<dim3(Y1D / 64, 2), 512, 0, stream>>>(proj, C_DIM, of32, Y1D,
        Y1D, C_DIM, Y1D, 0, nullptr, nullptr, (float*)d_out, nullptr, Y1D, 0);
}

// Round 18
// 160.960 us; speedup vs baseline: 1.9000x; 1.1233x over previous
//
#include <hip/hip_runtime.h>
#include <math.h>

typedef unsigned short u16;
typedef unsigned int   u32;

typedef __bf16 bf16x8 __attribute__((ext_vector_type(8)));
typedef float  f32x4  __attribute__((ext_vector_type(4)));

#define C_DIM 256
#define D_DIM 8192
#define HIDD  4096
#define Y1D   2048

__device__ __forceinline__ u16 f2bf(float f) {
    union { float f; u32 u; } v; v.f = f;
    u32 r = v.u + 0x7fffu + ((v.u >> 16) & 1u);   // RNE
    return (u16)(r >> 16);
}
__device__ __forceinline__ float geluf(float x) {
    return 0.5f * x * (1.0f + erff(x * 0.70710678118654752f));
}
// LDS swizzle: 16B chunk kg within a 64B row, XOR'd by row bits -> low-conflict reads
__device__ __forceinline__ int swz(int row, int kg) {
    return row * 64 + (((kg) ^ ((row >> 1) & 3)) << 4);
}
// fp32 LDS swizzle for the filter row buffer
__device__ __forceinline__ int xsw(int t) {
    int ch = t >> 2;
    return (((ch ^ ((ch >> 3) & 7))) << 2) | (t & 3);
}
// async global->LDS, 16B per lane; lds dest wave-uniform base (lane*16 implicit)
__device__ __forceinline__ void gload16(const void* g, void* l) {
    __builtin_amdgcn_global_load_lds(
        (const __attribute__((address_space(1))) void*)g,
        (__attribute__((address_space(3))) void*)l, 16, 0, 0);
}

// ---- per-row: weight-net coefs (fused), Z=FIR(c,X-mu) bf16, Xo bf16, X bf16 ----
__global__ __launch_bounds__(256) void filterk(const float* __restrict__ X,
                                               const float* __restrict__ w1,
                                               const float* __restrict__ b1,
                                               const float* __restrict__ w2,
                                               const float* __restrict__ b2,
                                               u16* __restrict__ Zb,
                                               u16* __restrict__ Xob,
                                               u16* __restrict__ Xb) {
    __shared__ float Xl[8240];
    __shared__ float wl[65];
    __shared__ float cl[40];
    __shared__ float red[4];
    int i = blockIdx.x, tid = threadIdx.x;
    int lane = tid & 63, wv = tid >> 6;
    const float* row = X + (size_t)i * D_DIM;
    float s = 0.f;
    #pragma unroll
    for (int q = 0; q < 8; ++q) {
        int t = tid * 32 + q * 4;
        float4 v = *(const float4*)(row + t);
        s += v.x + v.y + v.z + v.w;
        *(float4*)(Xl + xsw(t)) = v;
    }
    float w1l = w1[lane], b1l = b1[lane], w2l = w2[lane], b2l = b2[0];
    for (int li = wv; li < 65; li += 4) {
        float lag = (float)(li - 32);
        float h = geluf(lag * w1l + b1l);
        float p = h * w2l;
        #pragma unroll
        for (int off = 32; off; off >>= 1) p += __shfl_xor(p, off);
        if (lane == 0) wl[li] = p + b2l;
    }
    #pragma unroll
    for (int off = 32; off; off >>= 1) s += __shfl_xor(s, off);
    if (lane == 0) red[wv] = s;
    __syncthreads();
    if (tid <= 32) {
        cl[tid] = (tid == 0) ? wl[32] / (float)D_DIM
                             : (wl[32 - tid] + wl[32 + tid]) / ((float)D_DIM - (float)tid);
    }
    if (tid == 33) {
        float ssum = wl[32] / (float)D_DIM;
        for (int k = 1; k <= 32; ++k) ssum += (wl[32 - k] + wl[32 + k]) / ((float)D_DIM - (float)k);
        cl[33] = ssum;
    }
    float mu = (red[0] + red[1] + red[2] + red[3]) * (1.f / (float)D_DIM);
    if (tid < 10) {
        float4 mv = make_float4(mu, mu, mu, mu);
        *(float4*)(Xl + xsw(D_DIM + tid * 4)) = mv;
    }
    __syncthreads();
    float csum = cl[33];
    #pragma unroll
    for (int ch = 0; ch < 8; ++ch) {
        int t4 = tid * 32 + ch * 4;
        float w[40] __attribute__((aligned(16)));
        #pragma unroll
        for (int g = 0; g < 10; ++g)
            *(float4*)(w + g * 4) = *(const float4*)(Xl + xsw(t4 + g * 4));
        u16 zb[4], xo[4], xb[4];
        #pragma unroll
        for (int j = 0; j < 4; ++j) {
            float a = 0.f;
            #pragma unroll
            for (int k = 0; k < 33; ++k) a = fmaf(cl[k], w[j + k], a);
            zb[j] = f2bf(a - mu * csum);
            xo[j] = f2bf(w[j] - mu);
            xb[j] = f2bf(w[j]);
        }
        uint2 zp, op, bp;
        zp.x = (u32)zb[0] | ((u32)zb[1] << 16); zp.y = (u32)zb[2] | ((u32)zb[3] << 16);
        op.x = (u32)xo[0] | ((u32)xo[1] << 16); op.y = (u32)xo[2] | ((u32)xo[3] << 16);
        bp.x = (u32)xb[0] | ((u32)xb[1] << 16); bp.y = (u32)xb[2] | ((u32)xb[3] << 16);
        *(uint2*)(Zb  + (size_t)i * D_DIM + t4) = zp;
        *(uint2*)(Xob + (size_t)i * D_DIM + t4) = op;
        *(uint2*)(Xb  + (size_t)i * D_DIM + t4) = bp;
    }
}

// ------- unified bf16 MFMA GEMM (R12-proven sync structure) --------------------
// MODE 0: bf16 split-K partials; MODE 2: fp32 out; MODE 3: gelu(acc+V+bias) bf16.
// ASRC 0: A bf16 gload_lds; ASRC 1: A fp32 reg-convert.
// BSRC 0: B fp32, 2n x 4k/thread (BN=64); BSRC 1: B bf16 NT gload_lds;
// BSRC 2: B bf16 NN u16 scatter; BSRC 3: B fp32, 8k x 1n/thread -> ds_write_b128
//         (BN=128: 512B-contiguous DRAM runs per k-row, one b128 LDS write).
template<int MODE, int ASRC, int BSRC, int BN, int KS>
__global__ __launch_bounds__(512) void gemm_u(
    const void* __restrict__ Av, int lda,
    const void* __restrict__ Bv, int ldb,
    int N, int sliceLen, int nHalf, long long bHalfOff,
    const float* __restrict__ Vadd, const float* __restrict__ bias,
    float* __restrict__ outF, u16* __restrict__ outB,
    int ldc, int partStride)
{
    constexpr int NI = BN / 32;
    __shared__ u16 Alds[2][256 * 32];
    __shared__ u16 Blds[2][BN * 32];
    const int tid = threadIdx.x;
    const int bid = blockIdx.x;
    const int ks  = bid % KS;              // ks fastest -> same-ks blocks share an XCD
    const int nb0 = (bid / KS) * BN;
    const int mt  = blockIdx.y;
    const int k0base = ks * sliceLen;
    const int ksteps = sliceLen >> 5;
    const int lane = tid & 63, wid = tid >> 6;
    const int wm = wid >> 1, wn = wid & 1;
    const int l15 = lane & 15, kg = lane >> 4;

    const int inH2 = (nb0 >= nHalf) ? 1 : 0;
    const int nbB  = nb0 - (inH2 ? nHalf : 0);

    const u16* gA0 = nullptr; const u16* gA1 = nullptr;
    {
        int r0 = wid * 32 + (lane >> 2);
        int r1 = r0 + 16;
        int c0 = (lane & 3) ^ ((r0 >> 1) & 3);
        int c1 = (lane & 3) ^ ((r1 >> 1) & 3);
        gA0 = (const u16*)Av + (size_t)(mt * 256 + r0) * lda + k0base + c0 * 8;
        gA1 = (const u16*)Av + (size_t)(mt * 256 + r1) * lda + k0base + c1 * 8;
    }
    const int sArow = tid >> 1, sAe = (tid & 1) * 16;
    const float* ApF = (const float*)Av + (size_t)(mt * 256 + sArow) * lda + sAe + k0base;
    const int aw0 = swz(sArow, sAe >> 3);
    const int aw1 = swz(sArow, (sAe >> 3) + 1);
    float4 fa0, fa1, fa2, fa3;

    // BSRC 0 (BN=64): thread covers 2n x 4k
    const int n2 = (tid & 31) * 2;
    const int k4 = ((tid >> 5) & 7) * 4;
    const float* BpF = (const float*)Bv + (inH2 ? (size_t)bHalfOff : 0)
                     + (size_t)(k0base + k4) * ldb + nbB + n2;
    const int bwc0 = swz(n2,     k4 >> 3) + (k4 & 4) * 2;
    const int bwc1 = swz(n2 + 1, k4 >> 3) + (k4 & 4) * 2;
    float2 Lb0, Lb1, Lb2, Lb3;
    // BSRC 1: bf16 NT gload
    const u16* gB0 = nullptr;
    if constexpr (BSRC == 1) {
        int tr = wid * 16 + (lane >> 2);
        int c  = (lane & 3) ^ ((tr >> 1) & 3);
        gB0 = (const u16*)Bv + (size_t)(nb0 + tr) * ldb + k0base + c * 8;
    }
    // BSRC 2: bf16 NN scatter
    const int sBk = tid >> 4, sBn2 = (tid & 15) * 2;
    const u16* BpH = (const u16*)Bv + (size_t)(k0base + sBk) * ldb + nbB + sBn2;
    const int bh0 = swz(sBn2,     sBk >> 3) + (sBk & 7) * 2;
    const int bh1 = swz(sBn2 + 1, sBk >> 3) + (sBk & 7) * 2;
    u32 bhv = 0;
    // BSRC 3 (BN=128): thread covers 8k x 1n; one b128 LDS write
    const int b3n = tid & 127;
    const int b3k = (tid >> 7) * 8;
    const float* Bp3 = (const float*)Bv + (inH2 ? (size_t)bHalfOff : 0)
                     + (size_t)(k0base + b3k) * ldb + nbB + b3n;
    const int bw3 = swz(b3n, b3k >> 3);
    float b3v[8];

    int aoff[4], boff[NI];
    #pragma unroll
    for (int mi = 0; mi < 4; ++mi) { int r = wm * 64 + mi * 16 + l15; aoff[mi] = swz(r, kg); }
    #pragma unroll
    for (int ni = 0; ni < NI; ++ni) { int r = wn * (BN / 2) + ni * 16 + l15; boff[ni] = swz(r, kg); }

    auto stageGL = [&](int kt, int pb) {
        if constexpr (ASRC == 0) {
            char* ab = (char*)&Alds[pb][0] + wid * 2048;
            gload16(gA0 + (kt << 5), ab);
            gload16(gA1 + (kt << 5), ab + 1024);
        }
        if constexpr (BSRC == 1) {
            if (wid < BN / 16) {
                char* bb = (char*)&Blds[pb][0] + wid * 1024;
                gload16(gB0 + (kt << 5), bb);
            }
        }
    };
    auto loadA = [&](int kt) {
        const float* ap = ApF + (kt << 5);
        fa0 = *(const float4*)(ap);     fa1 = *(const float4*)(ap + 4);
        fa2 = *(const float4*)(ap + 8); fa3 = *(const float4*)(ap + 12);
    };
    auto writeA = [&](int pb) {
        char* AB = (char*)&Alds[pb][0];
        int4 w0, w1;
        w0.x = (int)((u32)f2bf(fa0.x) | ((u32)f2bf(fa0.y) << 16));
        w0.y = (int)((u32)f2bf(fa0.z) | ((u32)f2bf(fa0.w) << 16));
        w0.z = (int)((u32)f2bf(fa1.x) | ((u32)f2bf(fa1.y) << 16));
        w0.w = (int)((u32)f2bf(fa1.z) | ((u32)f2bf(fa1.w) << 16));
        w1.x = (int)((u32)f2bf(fa2.x) | ((u32)f2bf(fa2.y) << 16));
        w1.y = (int)((u32)f2bf(fa2.z) | ((u32)f2bf(fa2.w) << 16));
        w1.z = (int)((u32)f2bf(fa3.x) | ((u32)f2bf(fa3.y) << 16));
        w1.w = (int)((u32)f2bf(fa3.z) | ((u32)f2bf(fa3.w) << 16));
        *(int4*)(AB + aw0) = w0;
        *(int4*)(AB + aw1) = w1;
    };
    auto loadB = [&](int kt) {
        if constexpr (BSRC == 0) {
            if (tid < 256) {
                const float* bp = BpF + (size_t)(kt << 5) * ldb;
                Lb0 = *(const float2*)(bp);
                Lb1 = *(const float2*)(bp + ldb);
                Lb2 = *(const float2*)(bp + 2 * ldb);
                Lb3 = *(const float2*)(bp + 3 * ldb);
            }
        } else if constexpr (BSRC == 2) {
            bhv = *(const u32*)(BpH + (size_t)(kt << 5) * ldb);
        } else if constexpr (BSRC == 3) {
            const float* bp = Bp3 + (size_t)(kt << 5) * ldb;
            #pragma unroll
            for (int j = 0; j < 8; ++j) b3v[j] = bp[(size_t)j * ldb];
        }
    };
    auto writeB = [&](int pb) {
        char* BB = (char*)&Blds[pb][0];
        if constexpr (BSRC == 0) {
            if (tid < 256) {
                uint2 p0, p1;
                p0.x = (u32)f2bf(Lb0.x) | ((u32)f2bf(Lb1.x) << 16);
                p0.y = (u32)f2bf(Lb2.x) | ((u32)f2bf(Lb3.x) << 16);
                p1.x = (u32)f2bf(Lb0.y) | ((u32)f2bf(Lb1.y) << 16);
                p1.y = (u32)f2bf(Lb2.y) | ((u32)f2bf(Lb3.y) << 16);
                *(uint2*)(BB + bwc0) = p0;
                *(uint2*)(BB + bwc1) = p1;
            }
        } else if constexpr (BSRC == 2) {
            *(u16*)(BB + bh0) = (u16)(bhv & 0xffffu);
            *(u16*)(BB + bh1) = (u16)(bhv >> 16);
        } else if constexpr (BSRC == 3) {
            uint4 p;
            p.x = (u32)f2bf(b3v[0]) | ((u32)f2bf(b3v[1]) << 16);
            p.y = (u32)f2bf(b3v[2]) | ((u32)f2bf(b3v[3]) << 16);
            p.z = (u32)f2bf(b3v[4]) | ((u32)f2bf(b3v[5]) << 16);
            p.w = (u32)f2bf(b3v[6]) | ((u32)f2bf(b3v[7]) << 16);
            *(uint4*)(BB + bw3) = p;
        }
    };

    f32x4 acc[4][NI];
    #pragma unroll
    for (int mi = 0; mi < 4; ++mi)
        #pragma unroll
        for (int ni = 0; ni < NI; ++ni) { f32x4 zz = {0.f, 0.f, 0.f, 0.f}; acc[mi][ni] = zz; }

    auto mfmaStep = [&](int pb) {
        const char* AB = (const char*)&Alds[pb][0];
        const char* BB = (const char*)&Blds[pb][0];
        bf16x8 af[4], bfr[NI];
        #pragma unroll
        for (int mi = 0; mi < 4; ++mi) af[mi] = *(const bf16x8*)(AB + aoff[mi]);
        #pragma unroll
        for (int ni = 0; ni < NI; ++ni) bfr[ni] = *(const bf16x8*)(BB + boff[ni]);
        #pragma unroll
        for (int mi = 0; mi < 4; ++mi)
            #pragma unroll
            for (int ni = 0; ni < NI; ++ni)
                acc[mi][ni] = __builtin_amdgcn_mfma_f32_16x16x32_bf16(af[mi], bfr[ni], acc[mi][ni], 0, 0, 0);
    };

    stageGL(0, 0);
    if constexpr (ASRC == 1) { loadA(0); writeA(0); loadA(1); }
    if constexpr (BSRC == 0 || BSRC == 2 || BSRC == 3) { loadB(0); writeB(0); loadB(1); }
    __syncthreads();
    for (int kt = 0; kt < ksteps; ++kt) {
        const int pb = kt & 1;
        if (kt + 1 < ksteps) {
            stageGL(kt + 1, pb ^ 1);
            if constexpr (ASRC == 1) writeA(pb ^ 1);
            if constexpr (BSRC == 0 || BSRC == 2 || BSRC == 3) writeB(pb ^ 1);
        }
        if (kt + 2 < ksteps) {
            if constexpr (ASRC == 1) loadA(kt + 2);
            if constexpr (BSRC == 0 || BSRC == 2 || BSRC == 3) loadB(kt + 2);
        }
        mfmaStep(pb);
        __syncthreads();
    }

    const int rq = lane >> 4;
    #pragma unroll
    for (int mi = 0; mi < 4; ++mi)
        #pragma unroll
        for (int ni = 0; ni < NI; ++ni)
            #pragma unroll
            for (int r = 0; r < 4; ++r) {
                int m = wm * 64 + mi * 16 + rq * 4 + r;
                int n = nb0 + wn * (BN / 2) + ni * 16 + l15;
                float v = acc[mi][ni][r];
                if (MODE == 0)
                    outB[(size_t)ks * partStride + (size_t)m * N + n] = f2bf(v);
                else if (MODE == 2)
                    outF[(size_t)(mt * 256 + m) * ldc + n] = v;
                else {
                    float h = geluf(v + Vadd[(size_t)m * N + n] + bias[n]);
                    outB[(size_t)m * ldc + n] = f2bf(h);
                }
            }
}

// -------- sum 32 bf16 cov partials -> covbf ------------------------------------
__global__ __launch_bounds__(256) void reduce_cov(const u16* __restrict__ parts,
                                                  u16* __restrict__ out) {
    int i8 = (blockIdx.x * 256 + threadIdx.x) * 8;   // grid 32 -> 65536
    float s[8] = {};
    #pragma unroll
    for (int sl = 0; sl < 32; ++sl) {
        uint4 v = *(const uint4*)(parts + (size_t)sl * 65536 + i8);
        u32 w[4] = {v.x, v.y, v.z, v.w};
        #pragma unroll
        for (int j = 0; j < 4; ++j) {
            union { u32 u; float f; } lo, hi;
            lo.u = (w[j] & 0xffffu) << 16; hi.u = w[j] & 0xffff0000u;
            s[2 * j] += lo.f; s[2 * j + 1] += hi.f;
        }
    }
    uint4 pk;
    pk.x = (u32)f2bf(s[0]) | ((u32)f2bf(s[1]) << 16);
    pk.y = (u32)f2bf(s[2]) | ((u32)f2bf(s[3]) << 16);
    pk.z = (u32)f2bf(s[4]) | ((u32)f2bf(s[5]) << 16);
    pk.w = (u32)f2bf(s[6]) | ((u32)f2bf(s[7]) << 16);
    *(uint4*)(out + i8) = pk;
}

// -------- fc1 partials (8 slices of 256x8192) -> V fp32 (n<4096) / Ubf (n>=4096)
__global__ __launch_bounds__(256) void reduce_vu(const u16* __restrict__ parts,
                                                 float* __restrict__ V,
                                                 u16* __restrict__ U) {
    int i8 = (blockIdx.x * 256 + threadIdx.x) * 8;   // grid 1024 -> 2M
    int m = i8 >> 13, n = i8 & 8191;
    float s[8] = {};
    #pragma unroll
    for (int sl = 0; sl < 8; ++sl) {
        uint4 v = *(const uint4*)(parts + (size_t)sl * (256 * 8192) + i8);
        u32 w[4] = {v.x, v.y, v.z, v.w};
        #pragma unroll
        for (int j = 0; j < 4; ++j) {
            union { u32 u; float f; } lo, hi;
            lo.u = (w[j] & 0xffffu) << 16; hi.u = w[j] & 0xffff0000u;
            s[2 * j] += lo.f; s[2 * j + 1] += hi.f;
        }
    }
    if (n < 4096) {
        float* vp = V + (size_t)m * 4096 + n;
        *(float4*)(vp)     = make_float4(s[0], s[1], s[2], s[3]);
        *(float4*)(vp + 4) = make_float4(s[4], s[5], s[6], s[7]);
    } else {
        uint4 pk;
        pk.x = (u32)f2bf(s[0]) | ((u32)f2bf(s[1]) << 16);
        pk.y = (u32)f2bf(s[2]) | ((u32)f2bf(s[3]) << 16);
        pk.z = (u32)f2bf(s[4]) | ((u32)f2bf(s[5]) << 16);
        pk.w = (u32)f2bf(s[6]) | ((u32)f2bf(s[7]) << 16);
        *(uint4*)(U + (size_t)m * 4096 + (n - 4096)) = pk;
    }
}

// -------- fc2 partials (32 slices) + bias + gelu -> of32 fp32 ------------------
__global__ __launch_bounds__(256) void reduce_fc32(const u16* __restrict__ parts,
                                                   const float* __restrict__ bias,
                                                   float* __restrict__ outF) {
    int i8 = (blockIdx.x * 256 + threadIdx.x) * 8;   // grid 256 -> 512K
    int col = i8 & (Y1D - 1);
    float s[8] = {};
    #pragma unroll
    for (int sl = 0; sl < 32; ++sl) {
        uint4 v = *(const uint4*)(parts + (size_t)sl * (256 * Y1D) + i8);
        u32 w[4] = {v.x, v.y, v.z, v.w};
        #pragma unroll
        for (int j = 0; j < 4; ++j) {
            union { u32 u; float f; } lo, hi;
            lo.u = (w[j] & 0xffffu) << 16; hi.u = w[j] & 0xffff0000u;
            s[2 * j] += lo.f; s[2 * j + 1] += hi.f;
        }
    }
    float4 b0 = *(const float4*)(bias + col);
    float4 b1 = *(const float4*)(bias + col + 4);
    s[0] = geluf(s[0] + b0.x); s[1] = geluf(s[1] + b0.y);
    s[2] = geluf(s[2] + b0.z); s[3] = geluf(s[3] + b0.w);
    s[4] = geluf(s[4] + b1.x); s[5] = geluf(s[5] + b1.y);
    s[6] = geluf(s[6] + b1.z); s[7] = geluf(s[7] + b1.w);
    *(float4*)(outF + i8)     = make_float4(s[0], s[1], s[2], s[3]);
    *(float4*)(outF + i8 + 4) = make_float4(s[4], s[5], s[6], s[7]);
}

extern "C" void kernel_launch(void* const* d_in, const int* in_sizes, int n_in,
                              void* d_out, int out_size, void* d_ws, size_t ws_size,
                              hipStream_t stream) {
    const float* X     = (const float*)d_in[0];
    const float* wn_w1 = (const float*)d_in[1];
    const float* wn_b1 = (const float*)d_in[2];
    const float* wn_w2 = (const float*)d_in[3];
    const float* wn_b2 = (const float*)d_in[4];
    const float* fc1_w = (const float*)d_in[5];
    const float* fc1_b = (const float*)d_in[6];
    const float* fc2_w = (const float*)d_in[7];
    const float* fc2_b = (const float*)d_in[8];
    const float* proj  = (const float*)d_in[9];

    char* ws = (char*)d_ws;
    size_t off = 0;
    auto alloc = [&](size_t bytes) { size_t o = off; off += (bytes + 255) & ~(size_t)255; return o; };
    u16*   Zb    = (u16*)  (ws + alloc((size_t)C_DIM * D_DIM * 2));
    u16*   Xob   = (u16*)  (ws + alloc((size_t)C_DIM * D_DIM * 2));
    u16*   Xb    = (u16*)  (ws + alloc((size_t)C_DIM * D_DIM * 2));
    u16*   covp  = (u16*)  (ws + alloc((size_t)32 * 65536 * 2));
    u16*   covbf = (u16*)  (ws + alloc((size_t)65536 * 2));
    u16*   p1b   = (u16*)  (ws + alloc((size_t)8 * C_DIM * D_DIM * 2));
    float* Vf    = (float*)(ws + alloc((size_t)C_DIM * HIDD * 4));
    u16*   Ubf   = (u16*)  (ws + alloc((size_t)C_DIM * HIDD * 2));
    u16*   hbf   = (u16*)  (ws + alloc((size_t)C_DIM * HIDD * 2));
    u16*   p2b   = (u16*)  (ws + alloc((size_t)32 * C_DIM * Y1D * 2));
    float* of32  = (float*)(ws + alloc((size_t)C_DIM * Y1D * 4));

    filterk<<<C_DIM, 256, 0, stream>>>(X, wn_w1, wn_b1, wn_w2, wn_b2, Zb, Xob, Xb);
    // cov partials: Zb @ Xob^T (A+B gload_lds), KS=32 -> 128 blocks (R12 proven)
    gemm_u<0, 0, 1, 64, 32><<<128, 512, 0, stream>>>(Zb, D_DIM, Xob, D_DIM,
        C_DIM, D_DIM / 32, C_DIM, 0, nullptr, nullptr, nullptr, covp, 0, 65536);
    reduce_cov<<<32, 256, 0, stream>>>(covp, covbf);
    // fc1 fused: Xb @ [W_top | W_bot], BN=128/KS=8 -> 512 blocks (2/CU), 8 slices
    gemm_u<0, 0, 3, 128, 8><<<(2 * HIDD / 128) * 8, 512, 0, stream>>>(Xb, D_DIM, fc1_w, HIDD,
        2 * HIDD, D_DIM / 8, HIDD, (long long)D_DIM * HIDD, nullptr, nullptr,
        nullptr, p1b, 0, C_DIM * 2 * HIDD);
    reduce_vu<<<1024, 256, 0, stream>>>(p1b, Vf, Ubf);
    // h = gelu(V + cov @ U + b1)  (K=256, A gload, B bf16 NN)
    gemm_u<3, 0, 2, 32, 1><<<HIDD / 32, 512, 0, stream>>>(covbf, C_DIM, Ubf, HIDD,
        HIDD, C_DIM, HIDD, 0, Vf, fc1_b, nullptr, hbf, HIDD, 0);
    // fc2: h @ fc2_w, BN=128/KS=32 -> 512 blocks (ksteps=4)
    gemm_u<0, 0, 3, 128, 32><<<(Y1D / 128) * 32, 512, 0, stream>>>(hbf, HIDD, fc2_w, Y1D,
        Y1D, HIDD / 32, 1 << 30, 0, nullptr, nullptr, nullptr, p2b, 0, C_DIM * Y1D);
    reduce_fc32<<<C_DIM * Y1D / 8 / 256, 256, 0, stream>>>(p2b, fc2_b, of32);
    // out = proj @ o   (A fp32 reg-convert; M=512 -> 2 m-tiles)
    gemm_u<2, 1, 0, 64, 1><<<dim3(Y1D / 64, 2), 512, 0, stream>>>(proj, C_DIM, of32, Y1D,
        Y1D, C_DIM, Y1D, 0, nullptr, nullptr, (float*)d_out, nullptr, Y1D, 0);
}